// Round 5
// baseline (537.047 us; speedup 1.0000x reference)
//
#include <hip/hip_runtime.h>

#define N_NODES 100000
#define N_EDGES 1600000
#define FDIM 64
#define NGRAPH 512
#define NB 782          // dst buckets of 128 nodes
#define NWG 256         // workgroups in hist/bin passes
#define CHUNK 6250      // E / NWG

// ================= 3-kernel exclusive scan (generic) =================
__global__ void scan_block(const int* __restrict__ in, int* __restrict__ excl,
                           int* __restrict__ blocksums, int n) {
    __shared__ int lds[256];
    int t = threadIdx.x;
    int base = blockIdx.x * 1024 + t * 4;
    int v0 = (base     < n) ? in[base]     : 0;
    int v1 = (base + 1 < n) ? in[base + 1] : 0;
    int v2 = (base + 2 < n) ? in[base + 2] : 0;
    int v3 = (base + 3 < n) ? in[base + 3] : 0;
    int s = v0 + v1 + v2 + v3;
    lds[t] = s;
    __syncthreads();
    for (int off = 1; off < 256; off <<= 1) {
        int x = (t >= off) ? lds[t - off] : 0;
        __syncthreads();
        lds[t] += x;
        __syncthreads();
    }
    int thrExcl = lds[t] - s;
    if (t == 255) blocksums[blockIdx.x] = lds[255];
    if (base     < n) excl[base]     = thrExcl;
    if (base + 1 < n) excl[base + 1] = thrExcl + v0;
    if (base + 2 < n) excl[base + 2] = thrExcl + v0 + v1;
    if (base + 3 < n) excl[base + 3] = thrExcl + v0 + v1 + v2;
}

__global__ void scan_top(int* __restrict__ blocksums, int nb, int* __restrict__ out, int n) {
    if (threadIdx.x == 0 && blockIdx.x == 0) {
        int run = 0;
        for (int i = 0; i < nb; ++i) { int v = blocksums[i]; blocksums[i] = run; run += v; }
        out[n] = run;
    }
}

__global__ void scan_add(int* __restrict__ out, const int* __restrict__ blocksums, int n) {
    int i = blockIdx.x * blockDim.x + threadIdx.x;
    if (i < n) out[i] += blocksums[i >> 10];
}

// ================= pass A: per-wg bucket histogram =================
__global__ __launch_bounds__(256) void hist_kernel(const int* __restrict__ dst,
                                                   int* __restrict__ hist, int E) {
    __shared__ int h[NB];
    int t = threadIdx.x, wg = blockIdx.x;
    for (int i = t; i < NB; i += 256) h[i] = 0;
    __syncthreads();
    int beg = wg * CHUNK, end = min(beg + CHUNK, E);
    for (int i = beg + t; i < end; i += 256) atomicAdd(&h[dst[i] >> 7], 1);
    __syncthreads();
    for (int i = t; i < NB; i += 256) hist[i * NWG + wg] = h[i];
}

// ================= pass B: binned append (LDS cursors, packed 4B edges) =================
__global__ __launch_bounds__(256) void bin_kernel(const int* __restrict__ src,
                                                  const int* __restrict__ dst,
                                                  const int* __restrict__ scannedH,
                                                  int* __restrict__ ebin, int E) {
    __shared__ int base[NB];
    __shared__ int cur[NB];
    int t = threadIdx.x, wg = blockIdx.x;
    for (int i = t; i < NB; i += 256) { base[i] = scannedH[i * NWG + wg]; cur[i] = 0; }
    __syncthreads();
    int beg = wg * CHUNK, end = min(beg + CHUNK, E);
    for (int i = beg + t; i < end; i += 256) {
        int d = dst[i];
        int b = d >> 7;
        int p = base[b] + atomicAdd(&cur[b], 1);
        ebin[p] = ((d & 127) << 17) | src[i];
    }
}

// ================= pass C: per-bucket sort + degree + dinv + offsets =================
__global__ __launch_bounds__(256) void csr_sort2(const int* __restrict__ ebin,
                                                 const int* __restrict__ scannedH,
                                                 int* __restrict__ csr_src,
                                                 int* __restrict__ offsets,
                                                 float* __restrict__ dinv, int E) {
    __shared__ int cnt[128];
    __shared__ int seg[128];
    __shared__ int cur[128];
    __shared__ int buf[4352];
    int t = threadIdx.x, b = blockIdx.x;
    int nbase = b << 7;
    int nodes = min(128, N_NODES - nbase);
    int bstart = scannedH[b * NWG];
    int bend = (b == NB - 1) ? E : scannedH[(b + 1) * NWG];
    if (t < 128) cnt[t] = 0;
    __syncthreads();
    // count per-node degree within bucket
    for (int i = bstart + t; i < bend; i += 256) atomicAdd(&cnt[ebin[i] >> 17], 1);
    __syncthreads();
    // inclusive scan of cnt -> seg (Hillis-Steele over 128)
    if (t < 128) seg[t] = cnt[t];
    __syncthreads();
    for (int off = 1; off < 128; off <<= 1) {
        int v = 0;
        if (t < 128 && t >= off) v = seg[t - off];
        __syncthreads();
        if (t < 128) seg[t] += v;
        __syncthreads();
    }
    if (t < nodes) {
        int excl = seg[t] - cnt[t];
        offsets[nbase + t] = bstart + excl;
        dinv[nbase + t] = rsqrtf((float)cnt[t] + 1.0f);   // +1 self loop
        cur[t] = excl;
    }
    if (b == 0 && t == 0) offsets[N_NODES] = E;
    __syncthreads();
    // place edges sorted by dstLocal
    for (int i = bstart + t; i < bend; i += 256) {
        int v = ebin[i];
        int p = atomicAdd(&cur[v >> 17], 1);
        buf[p] = v & 0x1FFFF;
    }
    __syncthreads();
    int span = bend - bstart;
    for (int i = t; i < span; i += 256) csr_src[bstart + i] = buf[i];
}

// ================= fused layer: Z = Â·in (gather), H = relu(Z@W + b) =================
// block = 256 threads = 4 waves, 64 dst nodes per block; lane = feature
template <bool PRESCALED, bool RELU, bool SCALE_OUT>
__global__ __launch_bounds__(256) void layer_fused(const float* __restrict__ in,
                                                   const int* __restrict__ csr_src,
                                                   const int* __restrict__ offsets,
                                                   const float* __restrict__ dinv,
                                                   const float* __restrict__ W,
                                                   const float* __restrict__ bias,
                                                   float* __restrict__ outb, int n) {
    __shared__ float Ws[64 * 64];
    __shared__ float Zs[64 * 65];   // Zs[feat*65 + localRow]
    int t = threadIdx.x;
    int nbase = blockIdx.x * 64;
    int w = t >> 6, lane = t & 63;

    #pragma unroll
    for (int k = 0; k < 16; ++k) Ws[t + k * 256] = W[t + k * 256];

    // ---- gather phase: wave w handles local rows [w*16, w*16+16) ----
    for (int i = 0; i < 16; ++i) {
        int r = w * 16 + i;
        int node = nbase + r;
        float z = 0.0f;
        if (node < n) {
            int beg = offsets[node], end = offsets[node + 1];
            float acc = 0.0f;
            int k = beg;
            for (; k + 3 < end; k += 4) {
                int s0 = csr_src[k], s1 = csr_src[k + 1], s2 = csr_src[k + 2], s3 = csr_src[k + 3];
                if (PRESCALED) {
                    acc += in[(size_t)s0 * FDIM + lane] + in[(size_t)s1 * FDIM + lane]
                         + in[(size_t)s2 * FDIM + lane] + in[(size_t)s3 * FDIM + lane];
                } else {
                    acc += in[(size_t)s0 * FDIM + lane] * dinv[s0]
                         + in[(size_t)s1 * FDIM + lane] * dinv[s1]
                         + in[(size_t)s2 * FDIM + lane] * dinv[s2]
                         + in[(size_t)s3 * FDIM + lane] * dinv[s3];
                }
            }
            for (; k < end; ++k) {
                int s = csr_src[k];
                float v = in[(size_t)s * FDIM + lane];
                acc += PRESCALED ? v : v * dinv[s];
            }
            float dd = dinv[node];
            float self = in[(size_t)node * FDIM + lane];
            if (!PRESCALED) self *= dd;
            z = dd * (acc + self);
        }
        Zs[lane * 65 + r] = z;
    }
    __syncthreads();

    // ---- GEMM phase: H[row][cg+j] = sum_k Z[row][k] * W[k][cg+j] + b ----
    int row = lane;
    int cg = w * 16;
    float acc2[16];
    #pragma unroll
    for (int j = 0; j < 16; ++j) acc2[j] = 0.0f;
    for (int k = 0; k < 64; ++k) {
        float zv = Zs[k * 65 + row];
        #pragma unroll
        for (int j = 0; j < 16; ++j) acc2[j] += zv * Ws[k * 64 + cg + j];
    }
    if (nbase + row < n) {
        float sc = SCALE_OUT ? dinv[nbase + row] : 1.0f;
        float* o = &outb[(size_t)(nbase + row) * FDIM + cg];
        #pragma unroll
        for (int j = 0; j < 16; ++j) {
            float v = acc2[j] + bias[cg + j];
            if (RELU) v = fmaxf(v, 0.0f);
            o[j] = v * sc;
        }
    }
}

// ================= pooling (batch sorted -> segmented reduction) =================
__global__ void gstart_kernel(const int* __restrict__ batch, int* __restrict__ gstart, int n) {
    int g = blockIdx.x * blockDim.x + threadIdx.x;
    if (g > NGRAPH) return;
    if (g == NGRAPH) { gstart[NGRAPH] = n; return; }
    int lo = 0, hi = n;
    while (lo < hi) {
        int mid = (lo + hi) >> 1;
        if (batch[mid] < g) lo = mid + 1; else hi = mid;
    }
    gstart[g] = lo;
}

__global__ __launch_bounds__(256) void pool2(const float* __restrict__ h,
                                             const int* __restrict__ gstart,
                                             float* __restrict__ out) {
    __shared__ float red[4][64];
    int g = blockIdx.x;
    int beg = gstart[g], end = gstart[g + 1];
    int w = threadIdx.x >> 6, lane = threadIdx.x & 63;
    float acc = 0.0f;
    for (int i = beg + w; i < end; i += 4)
        acc += h[(size_t)i * FDIM + lane];
    red[w][lane] = acc;
    __syncthreads();
    if (w == 0) {
        float tot = red[0][lane] + red[1][lane] + red[2][lane] + red[3][lane];
        float cnt = (float)(end - beg);
        out[(size_t)g * FDIM + lane] = tot / fmaxf(cnt, 1.0f);
    }
}

extern "C" void kernel_launch(void* const* d_in, const int* in_sizes, int n_in,
                              void* d_out, int out_size, void* d_ws, size_t ws_size,
                              hipStream_t stream) {
    const float* x     = (const float*)d_in[0];
    const int*   ei    = (const int*)d_in[1];
    const int*   batch = (const int*)d_in[2];
    const float* W1    = (const float*)d_in[3];
    const float* b1    = (const float*)d_in[4];
    const float* W2    = (const float*)d_in[5];
    const float* b2    = (const float*)d_in[6];
    const float* W3    = (const float*)d_in[7];
    const float* b3    = (const float*)d_in[8];
    float* out = (float*)d_out;

    const int N = N_NODES, E = N_EDGES;
    const int* src = ei;
    const int* dst = ei + E;

    // -------- workspace partition (bytes, 256-aligned) --------
    char* ws = (char*)d_ws;
    float* dinv     = (float*)(ws + 0);           //   400000 B
    int*   offsets  = (int*)  (ws + 400128);      //   400004 B (N+1)
    int*   csr_src  = (int*)  (ws + 800256);      //  6400000 B
    float* bufA     = (float*)(ws + 7200384);     // 25600000 B
    float* bufB     = (float*)(ws + 32800384);    // 25600000 B
    int*   gstart   = (int*)  (ws + 58400384);    //     2052 B
    // aliases into not-yet-live regions (dead before layer kernels):
    int*   scannedH   = (int*)(ws + 7200384);             // NB*NWG+1 ints (~801 KB) in bufA
    int*   blocksumsH = (int*)(ws + 7200384 + 1000448);   // 196 ints, in bufA
    int*   ebin       = (int*)(ws + 32800384);            // E ints (6.4 MB) in bufB

    // -------- bucketed counting sort -> CSR + degree/dinv/offsets --------
    hist_kernel<<<NWG, 256, 0, stream>>>(dst, scannedH, E);
    const int nH = NB * NWG;                // 200192
    const int nScanH = (nH + 1023) / 1024;  // 196
    scan_block<<<nScanH, 256, 0, stream>>>(scannedH, scannedH, blocksumsH, nH);
    scan_top<<<1, 64, 0, stream>>>(blocksumsH, nScanH, scannedH, nH);
    scan_add<<<(nH + 255) / 256, 256, 0, stream>>>(scannedH, blocksumsH, nH);
    bin_kernel<<<NWG, 256, 0, stream>>>(src, dst, scannedH, ebin, E);
    csr_sort2<<<NB, 256, 0, stream>>>(ebin, scannedH, csr_src, offsets, dinv, E);

    // -------- graph boundaries (batch sorted) --------
    gstart_kernel<<<3, 256, 0, stream>>>(batch, gstart, N);

    const int layerGrid = (N + 63) / 64;

    // ---- fused layers: in -> Â·in -> @W + b (+relu) (+dinv prescale for next) ----
    layer_fused<false, true,  true ><<<layerGrid, 256, 0, stream>>>(x,    csr_src, offsets, dinv, W1, b1, bufA, N);
    layer_fused<true,  true,  true ><<<layerGrid, 256, 0, stream>>>(bufA, csr_src, offsets, dinv, W2, b2, bufB, N);
    layer_fused<true,  false, false><<<layerGrid, 256, 0, stream>>>(bufB, csr_src, offsets, dinv, W3, b3, bufA, N);

    // ---- global mean pool (no atomics) ----
    pool2<<<NGRAPH, 256, 0, stream>>>(bufA, gstart, out);
}

// Round 6
// 372.471 us; speedup vs baseline: 1.4419x; 1.4419x over previous
//
#include <hip/hip_runtime.h>

#define N_NODES 100000
#define N_EDGES 1600000
#define FDIM 64
#define NGRAPH 512
#define NB 782          // dst buckets of 128 nodes
#define NWG 256         // workgroups in hist/bin passes
#define CHUNK 6250      // E / NWG

// ================= 3-kernel exclusive scan (generic) =================
__global__ void scan_block(const int* __restrict__ in, int* __restrict__ excl,
                           int* __restrict__ blocksums, int n) {
    __shared__ int lds[256];
    int t = threadIdx.x;
    int base = blockIdx.x * 1024 + t * 4;
    int v0 = (base     < n) ? in[base]     : 0;
    int v1 = (base + 1 < n) ? in[base + 1] : 0;
    int v2 = (base + 2 < n) ? in[base + 2] : 0;
    int v3 = (base + 3 < n) ? in[base + 3] : 0;
    int s = v0 + v1 + v2 + v3;
    lds[t] = s;
    __syncthreads();
    for (int off = 1; off < 256; off <<= 1) {
        int x = (t >= off) ? lds[t - off] : 0;
        __syncthreads();
        lds[t] += x;
        __syncthreads();
    }
    int thrExcl = lds[t] - s;
    if (t == 255) blocksums[blockIdx.x] = lds[255];
    if (base     < n) excl[base]     = thrExcl;
    if (base + 1 < n) excl[base + 1] = thrExcl + v0;
    if (base + 2 < n) excl[base + 2] = thrExcl + v0 + v1;
    if (base + 3 < n) excl[base + 3] = thrExcl + v0 + v1 + v2;
}

__global__ void scan_top(int* __restrict__ blocksums, int nb, int* __restrict__ out, int n) {
    if (threadIdx.x == 0 && blockIdx.x == 0) {
        int run = 0;
        for (int i = 0; i < nb; ++i) { int v = blocksums[i]; blocksums[i] = run; run += v; }
        out[n] = run;
    }
}

__global__ void scan_add(int* __restrict__ out, const int* __restrict__ blocksums, int n) {
    int i = blockIdx.x * blockDim.x + threadIdx.x;
    if (i < n) out[i] += blocksums[i >> 10];
}

// ================= pass A: per-wg bucket histogram =================
__global__ __launch_bounds__(256) void hist_kernel(const int* __restrict__ dst,
                                                   int* __restrict__ hist, int E) {
    __shared__ int h[NB];
    int t = threadIdx.x, wg = blockIdx.x;
    for (int i = t; i < NB; i += 256) h[i] = 0;
    __syncthreads();
    int beg = wg * CHUNK, end = min(beg + CHUNK, E);
    for (int i = beg + t; i < end; i += 256) atomicAdd(&h[dst[i] >> 7], 1);
    __syncthreads();
    for (int i = t; i < NB; i += 256) hist[i * NWG + wg] = h[i];
}

// ================= pass B: binned append (LDS cursors, packed 4B edges) =================
__global__ __launch_bounds__(256) void bin_kernel(const int* __restrict__ src,
                                                  const int* __restrict__ dst,
                                                  const int* __restrict__ scannedH,
                                                  int* __restrict__ ebin, int E) {
    __shared__ int base[NB];
    __shared__ int cur[NB];
    int t = threadIdx.x, wg = blockIdx.x;
    for (int i = t; i < NB; i += 256) { base[i] = scannedH[i * NWG + wg]; cur[i] = 0; }
    __syncthreads();
    int beg = wg * CHUNK, end = min(beg + CHUNK, E);
    for (int i = beg + t; i < end; i += 256) {
        int d = dst[i];
        int b = d >> 7;
        int p = base[b] + atomicAdd(&cur[b], 1);
        ebin[p] = ((d & 127) << 17) | src[i];
    }
}

// ================= pass C: per-bucket sort + degree + dinv + offsets =================
__global__ __launch_bounds__(256) void csr_sort2(const int* __restrict__ ebin,
                                                 const int* __restrict__ scannedH,
                                                 int* __restrict__ csr_src,
                                                 int* __restrict__ offsets,
                                                 float* __restrict__ dinv, int E) {
    __shared__ int cnt[128];
    __shared__ int seg[128];
    __shared__ int cur[128];
    __shared__ int buf[4352];
    int t = threadIdx.x, b = blockIdx.x;
    int nbase = b << 7;
    int nodes = min(128, N_NODES - nbase);
    int bstart = scannedH[b * NWG];
    int bend = (b == NB - 1) ? E : scannedH[(b + 1) * NWG];
    if (t < 128) cnt[t] = 0;
    __syncthreads();
    for (int i = bstart + t; i < bend; i += 256) atomicAdd(&cnt[ebin[i] >> 17], 1);
    __syncthreads();
    if (t < 128) seg[t] = cnt[t];
    __syncthreads();
    for (int off = 1; off < 128; off <<= 1) {
        int v = 0;
        if (t < 128 && t >= off) v = seg[t - off];
        __syncthreads();
        if (t < 128) seg[t] += v;
        __syncthreads();
    }
    if (t < nodes) {
        int excl = seg[t] - cnt[t];
        offsets[nbase + t] = bstart + excl;
        dinv[nbase + t] = rsqrtf((float)cnt[t] + 1.0f);   // +1 self loop
        cur[t] = excl;
    }
    if (b == 0 && t == 0) offsets[N_NODES] = E;
    __syncthreads();
    for (int i = bstart + t; i < bend; i += 256) {
        int v = ebin[i];
        int p = atomicAdd(&cur[v >> 17], 1);
        buf[p] = v & 0x1FFFF;
    }
    __syncthreads();
    int span = bend - bstart;
    for (int i = t; i < span; i += 256) csr_src[bstart + i] = buf[i];
}

// ================= fp32 GEMM: Hs = (X @ W) * dinv[row] =================
__global__ __launch_bounds__(256) void gemm64(const float* __restrict__ X,
                                              const float* __restrict__ W,
                                              const float* __restrict__ dinv,
                                              float* __restrict__ Hout, int n) {
    __shared__ float Ws[64 * 64];
    __shared__ float Xs[64 * 65];
    int t = threadIdx.x;
    int r0 = blockIdx.x * 64;

    #pragma unroll
    for (int k = 0; k < 16; ++k) Ws[t + k * 256] = W[t + k * 256];

    #pragma unroll
    for (int k = 0; k < 16; ++k) {
        int idx = t + k * 256;
        int row = idx >> 6, col = idx & 63;
        float v = (r0 + row < n) ? X[(size_t)(r0 + row) * FDIM + col] : 0.0f;
        Xs[col * 65 + row] = v;
    }
    __syncthreads();

    int row = t & 63;
    int cg  = (t >> 6) * 16;
    float acc[16];
    #pragma unroll
    for (int j = 0; j < 16; ++j) acc[j] = 0.0f;

    for (int k = 0; k < 64; ++k) {
        float xv = Xs[k * 65 + row];
        #pragma unroll
        for (int j = 0; j < 16; ++j) acc[j] += xv * Ws[k * 64 + cg + j];
    }

    if (r0 + row < n) {
        float sc = dinv[r0 + row];
        float* o = &Hout[(size_t)(r0 + row) * FDIM + cg];
        #pragma unroll
        for (int j = 0; j < 16; ++j) o[j] = acc[j] * sc;
    }
}

// ================= gather aggregation (fused self-loop + bias + relu) =================
// one wave per dst node, lane = feature; hs prescaled by dinv. unroll-8, 2 accumulators.
__global__ __launch_bounds__(256) void gather_agg(const float* __restrict__ hs,
                                                  const int* __restrict__ csr_src,
                                                  const int* __restrict__ offsets,
                                                  const float* __restrict__ dinv,
                                                  const float* __restrict__ bias,
                                                  float* __restrict__ outb,
                                                  int n, int do_relu) {
    int node = blockIdx.x * 4 + (threadIdx.x >> 6);
    int lane = threadIdx.x & 63;
    if (node >= n) return;
    int beg = offsets[node], end = offsets[node + 1];
    float accA = 0.0f, accB = 0.0f;
    int k = beg;
    for (; k + 7 < end; k += 8) {
        int s0 = csr_src[k],     s1 = csr_src[k + 1], s2 = csr_src[k + 2], s3 = csr_src[k + 3];
        int s4 = csr_src[k + 4], s5 = csr_src[k + 5], s6 = csr_src[k + 6], s7 = csr_src[k + 7];
        float a0 = hs[(size_t)s0 * FDIM + lane];
        float a1 = hs[(size_t)s1 * FDIM + lane];
        float a2 = hs[(size_t)s2 * FDIM + lane];
        float a3 = hs[(size_t)s3 * FDIM + lane];
        float a4 = hs[(size_t)s4 * FDIM + lane];
        float a5 = hs[(size_t)s5 * FDIM + lane];
        float a6 = hs[(size_t)s6 * FDIM + lane];
        float a7 = hs[(size_t)s7 * FDIM + lane];
        accA += (a0 + a1) + (a2 + a3);
        accB += (a4 + a5) + (a6 + a7);
    }
    for (; k + 3 < end; k += 4) {
        int s0 = csr_src[k], s1 = csr_src[k + 1], s2 = csr_src[k + 2], s3 = csr_src[k + 3];
        accA += hs[(size_t)s0 * FDIM + lane] + hs[(size_t)s1 * FDIM + lane];
        accB += hs[(size_t)s2 * FDIM + lane] + hs[(size_t)s3 * FDIM + lane];
    }
    for (; k < end; ++k) accA += hs[(size_t)csr_src[k] * FDIM + lane];

    float dd = dinv[node];
    float v = dd * ((accA + accB) + hs[(size_t)node * FDIM + lane]) + bias[lane];
    if (do_relu) v = fmaxf(v, 0.0f);
    outb[(size_t)node * FDIM + lane] = v;
}

// ================= pooling (batch sorted -> segmented reduction) =================
__global__ void gstart_kernel(const int* __restrict__ batch, int* __restrict__ gstart, int n) {
    int g = blockIdx.x * blockDim.x + threadIdx.x;
    if (g > NGRAPH) return;
    if (g == NGRAPH) { gstart[NGRAPH] = n; return; }
    int lo = 0, hi = n;
    while (lo < hi) {
        int mid = (lo + hi) >> 1;
        if (batch[mid] < g) lo = mid + 1; else hi = mid;
    }
    gstart[g] = lo;
}

__global__ __launch_bounds__(256) void pool2(const float* __restrict__ h,
                                             const int* __restrict__ gstart,
                                             float* __restrict__ out) {
    __shared__ float red[4][64];
    int g = blockIdx.x;
    int beg = gstart[g], end = gstart[g + 1];
    int w = threadIdx.x >> 6, lane = threadIdx.x & 63;
    float acc = 0.0f;
    for (int i = beg + w; i < end; i += 4)
        acc += h[(size_t)i * FDIM + lane];
    red[w][lane] = acc;
    __syncthreads();
    if (w == 0) {
        float tot = red[0][lane] + red[1][lane] + red[2][lane] + red[3][lane];
        float cnt = (float)(end - beg);
        out[(size_t)g * FDIM + lane] = tot / fmaxf(cnt, 1.0f);
    }
}

extern "C" void kernel_launch(void* const* d_in, const int* in_sizes, int n_in,
                              void* d_out, int out_size, void* d_ws, size_t ws_size,
                              hipStream_t stream) {
    const float* x     = (const float*)d_in[0];
    const int*   ei    = (const int*)d_in[1];
    const int*   batch = (const int*)d_in[2];
    const float* W1    = (const float*)d_in[3];
    const float* b1    = (const float*)d_in[4];
    const float* W2    = (const float*)d_in[5];
    const float* b2    = (const float*)d_in[6];
    const float* W3    = (const float*)d_in[7];
    const float* b3    = (const float*)d_in[8];
    float* out = (float*)d_out;

    const int N = N_NODES, E = N_EDGES;
    const int* src = ei;
    const int* dst = ei + E;

    // -------- workspace partition (bytes, 256-aligned) --------
    char* ws = (char*)d_ws;
    float* dinv     = (float*)(ws + 0);           //   400000 B
    int*   offsets  = (int*)  (ws + 400128);      //   400004 B (N+1)
    int*   csr_src  = (int*)  (ws + 800256);      //  6400000 B
    float* bufA     = (float*)(ws + 7200384);     // 25600000 B
    float* bufB     = (float*)(ws + 32800384);    // 25600000 B
    int*   gstart   = (int*)  (ws + 58400384);    //     2052 B
    // aliases into not-yet-live regions (dead before layer kernels):
    int*   scannedH   = (int*)(ws + 7200384);             // NB*NWG+1 ints (~801 KB) in bufA
    int*   blocksumsH = (int*)(ws + 7200384 + 1000448);   // 196 ints, in bufA
    int*   ebin       = (int*)(ws + 32800384);            // E ints (6.4 MB) in bufB

    // -------- bucketed counting sort -> CSR + degree/dinv/offsets --------
    hist_kernel<<<NWG, 256, 0, stream>>>(dst, scannedH, E);
    const int nH = NB * NWG;                // 200192
    const int nScanH = (nH + 1023) / 1024;  // 196
    scan_block<<<nScanH, 256, 0, stream>>>(scannedH, scannedH, blocksumsH, nH);
    scan_top<<<1, 64, 0, stream>>>(blocksumsH, nScanH, scannedH, nH);
    scan_add<<<(nH + 255) / 256, 256, 0, stream>>>(scannedH, blocksumsH, nH);
    bin_kernel<<<NWG, 256, 0, stream>>>(src, dst, scannedH, ebin, E);
    csr_sort2<<<NB, 256, 0, stream>>>(ebin, scannedH, csr_src, offsets, dinv, E);

    // -------- graph boundaries (batch sorted) --------
    gstart_kernel<<<3, 256, 0, stream>>>(batch, gstart, N);

    const int gemmGrid   = (N + 63) / 64;
    const int gatherGrid = (N + 3) / 4;

    // ---- layer 1 ----  (gemm prescales rows by dinv; gather fuses self-loop+bias+relu)
    gemm64<<<gemmGrid, 256, 0, stream>>>(x, W1, dinv, bufA, N);
    gather_agg<<<gatherGrid, 256, 0, stream>>>(bufA, csr_src, offsets, dinv, b1, bufB, N, 1);

    // ---- layer 2 ----
    gemm64<<<gemmGrid, 256, 0, stream>>>(bufB, W2, dinv, bufA, N);
    gather_agg<<<gatherGrid, 256, 0, stream>>>(bufA, csr_src, offsets, dinv, b2, bufB, N, 1);

    // ---- layer 3 ----
    gemm64<<<gemmGrid, 256, 0, stream>>>(bufB, W3, dinv, bufA, N);
    gather_agg<<<gatherGrid, 256, 0, stream>>>(bufA, csr_src, offsets, dinv, b3, bufB, N, 0);

    // ---- global mean pool (no atomics) ----
    pool2<<<NGRAPH, 256, 0, stream>>>(bufB, gstart, out);
}

// Round 7
// 356.396 us; speedup vs baseline: 1.5069x; 1.0451x over previous
//
#include <hip/hip_runtime.h>

#define N_NODES 100000
#define N_EDGES 1600000
#define FDIM 64
#define NGRAPH 512
#define NB 782          // dst buckets of 128 nodes
#define NWG 256         // workgroups in hist/bin passes
#define CHUNK 6250      // E / NWG

__device__ __forceinline__ unsigned short f2bf(float v) {
    unsigned int x = __float_as_uint(v);
    x += 0x7FFF + ((x >> 16) & 1);          // RTNE
    return (unsigned short)(x >> 16);
}
__device__ __forceinline__ float bf2f(unsigned short u) {
    return __uint_as_float(((unsigned int)u) << 16);
}

// ================= 3-kernel exclusive scan (generic) =================
__global__ void scan_block(const int* __restrict__ in, int* __restrict__ excl,
                           int* __restrict__ blocksums, int n) {
    __shared__ int lds[256];
    int t = threadIdx.x;
    int base = blockIdx.x * 1024 + t * 4;
    int v0 = (base     < n) ? in[base]     : 0;
    int v1 = (base + 1 < n) ? in[base + 1] : 0;
    int v2 = (base + 2 < n) ? in[base + 2] : 0;
    int v3 = (base + 3 < n) ? in[base + 3] : 0;
    int s = v0 + v1 + v2 + v3;
    lds[t] = s;
    __syncthreads();
    for (int off = 1; off < 256; off <<= 1) {
        int x = (t >= off) ? lds[t - off] : 0;
        __syncthreads();
        lds[t] += x;
        __syncthreads();
    }
    int thrExcl = lds[t] - s;
    if (t == 255) blocksums[blockIdx.x] = lds[255];
    if (base     < n) excl[base]     = thrExcl;
    if (base + 1 < n) excl[base + 1] = thrExcl + v0;
    if (base + 2 < n) excl[base + 2] = thrExcl + v0 + v1;
    if (base + 3 < n) excl[base + 3] = thrExcl + v0 + v1 + v2;
}

__global__ void scan_top(int* __restrict__ blocksums, int nb, int* __restrict__ out, int n) {
    if (threadIdx.x == 0 && blockIdx.x == 0) {
        int run = 0;
        for (int i = 0; i < nb; ++i) { int v = blocksums[i]; blocksums[i] = run; run += v; }
        out[n] = run;
    }
}

__global__ void scan_add(int* __restrict__ out, const int* __restrict__ blocksums, int n) {
    int i = blockIdx.x * blockDim.x + threadIdx.x;
    if (i < n) out[i] += blocksums[i >> 10];
}

// ================= pass A: per-wg bucket histogram =================
__global__ __launch_bounds__(256) void hist_kernel(const int* __restrict__ dst,
                                                   int* __restrict__ hist, int E) {
    __shared__ int h[NB];
    int t = threadIdx.x, wg = blockIdx.x;
    for (int i = t; i < NB; i += 256) h[i] = 0;
    __syncthreads();
    int beg = wg * CHUNK, end = min(beg + CHUNK, E);
    for (int i = beg + t; i < end; i += 256) atomicAdd(&h[dst[i] >> 7], 1);
    __syncthreads();
    for (int i = t; i < NB; i += 256) hist[i * NWG + wg] = h[i];
}

// ================= pass B: binned append (LDS cursors, packed 4B edges) =================
__global__ __launch_bounds__(256) void bin_kernel(const int* __restrict__ src,
                                                  const int* __restrict__ dst,
                                                  const int* __restrict__ scannedH,
                                                  int* __restrict__ ebin, int E) {
    __shared__ int base[NB];
    __shared__ int cur[NB];
    int t = threadIdx.x, wg = blockIdx.x;
    for (int i = t; i < NB; i += 256) { base[i] = scannedH[i * NWG + wg]; cur[i] = 0; }
    __syncthreads();
    int beg = wg * CHUNK, end = min(beg + CHUNK, E);
    for (int i = beg + t; i < end; i += 256) {
        int d = dst[i];
        int b = d >> 7;
        int p = base[b] + atomicAdd(&cur[b], 1);
        ebin[p] = ((d & 127) << 17) | src[i];
    }
}

// ================= pass C: per-bucket sort + degree + dinv + offsets =================
__global__ __launch_bounds__(256) void csr_sort2(const int* __restrict__ ebin,
                                                 const int* __restrict__ scannedH,
                                                 int* __restrict__ csr_src,
                                                 int* __restrict__ offsets,
                                                 float* __restrict__ dinv, int E) {
    __shared__ int cnt[128];
    __shared__ int seg[128];
    __shared__ int cur[128];
    __shared__ int buf[4352];
    int t = threadIdx.x, b = blockIdx.x;
    int nbase = b << 7;
    int nodes = min(128, N_NODES - nbase);
    int bstart = scannedH[b * NWG];
    int bend = (b == NB - 1) ? E : scannedH[(b + 1) * NWG];
    if (t < 128) cnt[t] = 0;
    __syncthreads();
    for (int i = bstart + t; i < bend; i += 256) atomicAdd(&cnt[ebin[i] >> 17], 1);
    __syncthreads();
    if (t < 128) seg[t] = cnt[t];
    __syncthreads();
    for (int off = 1; off < 128; off <<= 1) {
        int v = 0;
        if (t < 128 && t >= off) v = seg[t - off];
        __syncthreads();
        if (t < 128) seg[t] += v;
        __syncthreads();
    }
    if (t < nodes) {
        int excl = seg[t] - cnt[t];
        offsets[nbase + t] = bstart + excl;
        dinv[nbase + t] = rsqrtf((float)cnt[t] + 1.0f);   // +1 self loop
        cur[t] = excl;
    }
    if (b == 0 && t == 0) offsets[N_NODES] = E;
    __syncthreads();
    for (int i = bstart + t; i < bend; i += 256) {
        int v = ebin[i];
        int p = atomicAdd(&cur[v >> 17], 1);
        buf[p] = v & 0x1FFFF;
    }
    __syncthreads();
    int span = bend - bstart;
    for (int i = t; i < span; i += 256) csr_src[bstart + i] = buf[i];
}

// ================= fp32 GEMM -> bf16 out: Hs = bf16((X @ W) * dinv[row]) =================
__global__ __launch_bounds__(256) void gemm64(const float* __restrict__ X,
                                              const float* __restrict__ W,
                                              const float* __restrict__ dinv,
                                              unsigned short* __restrict__ Hout, int n) {
    __shared__ float Ws[64 * 64];
    __shared__ float Xs[64 * 65];
    int t = threadIdx.x;
    int r0 = blockIdx.x * 64;

    #pragma unroll
    for (int k = 0; k < 16; ++k) Ws[t + k * 256] = W[t + k * 256];

    #pragma unroll
    for (int k = 0; k < 16; ++k) {
        int idx = t + k * 256;
        int row = idx >> 6, col = idx & 63;
        float v = (r0 + row < n) ? X[(size_t)(r0 + row) * FDIM + col] : 0.0f;
        Xs[col * 65 + row] = v;
    }
    __syncthreads();

    int row = t & 63;
    int cg  = (t >> 6) * 16;
    float acc[16];
    #pragma unroll
    for (int j = 0; j < 16; ++j) acc[j] = 0.0f;

    for (int k = 0; k < 64; ++k) {
        float xv = Xs[k * 65 + row];
        #pragma unroll
        for (int j = 0; j < 16; ++j) acc[j] += xv * Ws[k * 64 + cg + j];
    }

    if (r0 + row < n) {
        float sc = dinv[r0 + row];
        unsigned int* o = (unsigned int*)&Hout[(size_t)(r0 + row) * FDIM + cg];
        #pragma unroll
        for (int j = 0; j < 8; ++j) {
            unsigned int lo = f2bf(acc[2 * j]     * sc);
            unsigned int hi = f2bf(acc[2 * j + 1] * sc);
            o[j] = lo | (hi << 16);
        }
    }
}

// ================= gather aggregation over bf16 rows (fused self-loop+bias+relu) ===========
// one wave per dst node, lane = feature; hs prescaled by dinv, bf16. fp32 accumulate.
__global__ __launch_bounds__(256) void gather_agg(const unsigned short* __restrict__ hs,
                                                  const int* __restrict__ csr_src,
                                                  const int* __restrict__ offsets,
                                                  const float* __restrict__ dinv,
                                                  const float* __restrict__ bias,
                                                  float* __restrict__ outb,
                                                  int n, int do_relu) {
    int node = blockIdx.x * 4 + (threadIdx.x >> 6);
    int lane = threadIdx.x & 63;
    if (node >= n) return;
    int beg = offsets[node], end = offsets[node + 1];
    float accA = 0.0f, accB = 0.0f;
    int k = beg;
    for (; k + 7 < end; k += 8) {
        int s0 = csr_src[k],     s1 = csr_src[k + 1], s2 = csr_src[k + 2], s3 = csr_src[k + 3];
        int s4 = csr_src[k + 4], s5 = csr_src[k + 5], s6 = csr_src[k + 6], s7 = csr_src[k + 7];
        float a0 = bf2f(hs[(size_t)s0 * FDIM + lane]);
        float a1 = bf2f(hs[(size_t)s1 * FDIM + lane]);
        float a2 = bf2f(hs[(size_t)s2 * FDIM + lane]);
        float a3 = bf2f(hs[(size_t)s3 * FDIM + lane]);
        float a4 = bf2f(hs[(size_t)s4 * FDIM + lane]);
        float a5 = bf2f(hs[(size_t)s5 * FDIM + lane]);
        float a6 = bf2f(hs[(size_t)s6 * FDIM + lane]);
        float a7 = bf2f(hs[(size_t)s7 * FDIM + lane]);
        accA += (a0 + a1) + (a2 + a3);
        accB += (a4 + a5) + (a6 + a7);
    }
    for (; k + 3 < end; k += 4) {
        int s0 = csr_src[k], s1 = csr_src[k + 1], s2 = csr_src[k + 2], s3 = csr_src[k + 3];
        accA += bf2f(hs[(size_t)s0 * FDIM + lane]) + bf2f(hs[(size_t)s1 * FDIM + lane]);
        accB += bf2f(hs[(size_t)s2 * FDIM + lane]) + bf2f(hs[(size_t)s3 * FDIM + lane]);
    }
    for (; k < end; ++k) accA += bf2f(hs[(size_t)csr_src[k] * FDIM + lane]);

    float dd = dinv[node];
    float v = dd * ((accA + accB) + bf2f(hs[(size_t)node * FDIM + lane])) + bias[lane];
    if (do_relu) v = fmaxf(v, 0.0f);
    outb[(size_t)node * FDIM + lane] = v;
}

// ================= pooling (batch sorted -> segmented reduction) =================
__global__ void gstart_kernel(const int* __restrict__ batch, int* __restrict__ gstart, int n) {
    int g = blockIdx.x * blockDim.x + threadIdx.x;
    if (g > NGRAPH) return;
    if (g == NGRAPH) { gstart[NGRAPH] = n; return; }
    int lo = 0, hi = n;
    while (lo < hi) {
        int mid = (lo + hi) >> 1;
        if (batch[mid] < g) lo = mid + 1; else hi = mid;
    }
    gstart[g] = lo;
}

__global__ __launch_bounds__(256) void pool2(const float* __restrict__ h,
                                             const int* __restrict__ gstart,
                                             float* __restrict__ out) {
    __shared__ float red[4][64];
    int g = blockIdx.x;
    int beg = gstart[g], end = gstart[g + 1];
    int w = threadIdx.x >> 6, lane = threadIdx.x & 63;
    float acc = 0.0f;
    for (int i = beg + w; i < end; i += 4)
        acc += h[(size_t)i * FDIM + lane];
    red[w][lane] = acc;
    __syncthreads();
    if (w == 0) {
        float tot = red[0][lane] + red[1][lane] + red[2][lane] + red[3][lane];
        float cnt = (float)(end - beg);
        out[(size_t)g * FDIM + lane] = tot / fmaxf(cnt, 1.0f);
    }
}

extern "C" void kernel_launch(void* const* d_in, const int* in_sizes, int n_in,
                              void* d_out, int out_size, void* d_ws, size_t ws_size,
                              hipStream_t stream) {
    const float* x     = (const float*)d_in[0];
    const int*   ei    = (const int*)d_in[1];
    const int*   batch = (const int*)d_in[2];
    const float* W1    = (const float*)d_in[3];
    const float* b1    = (const float*)d_in[4];
    const float* W2    = (const float*)d_in[5];
    const float* b2    = (const float*)d_in[6];
    const float* W3    = (const float*)d_in[7];
    const float* b3    = (const float*)d_in[8];
    float* out = (float*)d_out;

    const int N = N_NODES, E = N_EDGES;
    const int* src = ei;
    const int* dst = ei + E;

    // -------- workspace partition (bytes, 256-aligned) --------
    char* ws = (char*)d_ws;
    float*          dinv    = (float*)         (ws + 0);         //   400000 B
    int*            offsets = (int*)           (ws + 400128);    //   400004 B (N+1)
    int*            csr_src = (int*)           (ws + 800256);    //  6400000 B
    float*          bufA    = (float*)         (ws + 7200384);   // 25600000 B (fp32 gather out / gemm in)
    unsigned short* hbf     = (unsigned short*)(ws + 32800384);  // 12800000 B (bf16 gemm out / gather in)
    int*            gstart  = (int*)           (ws + 45600384);  //     2052 B
    // aliases into bufA (dead before layer kernels):
    int* scannedH   = (int*)(ws + 7200384);            // NB*NWG+1 ints (~801 KB)
    int* blocksumsH = (int*)(ws + 8201216);            // 196 ints
    int* ebin       = (int*)(ws + 8202240);            // E ints (6.4 MB)

    // -------- bucketed counting sort -> CSR + degree/dinv/offsets --------
    hist_kernel<<<NWG, 256, 0, stream>>>(dst, scannedH, E);
    const int nH = NB * NWG;                // 200192
    const int nScanH = (nH + 1023) / 1024;  // 196
    scan_block<<<nScanH, 256, 0, stream>>>(scannedH, scannedH, blocksumsH, nH);
    scan_top<<<1, 64, 0, stream>>>(blocksumsH, nScanH, scannedH, nH);
    scan_add<<<(nH + 255) / 256, 256, 0, stream>>>(scannedH, blocksumsH, nH);
    bin_kernel<<<NWG, 256, 0, stream>>>(src, dst, scannedH, ebin, E);
    csr_sort2<<<NB, 256, 0, stream>>>(ebin, scannedH, csr_src, offsets, dinv, E);

    // -------- graph boundaries (batch sorted) --------
    gstart_kernel<<<3, 256, 0, stream>>>(batch, gstart, N);

    const int gemmGrid   = (N + 63) / 64;
    const int gatherGrid = (N + 3) / 4;

    // ---- layer 1 ----  (gemm prescales by dinv, outputs bf16; gather accumulates fp32)
    gemm64<<<gemmGrid, 256, 0, stream>>>(x, W1, dinv, hbf, N);
    gather_agg<<<gatherGrid, 256, 0, stream>>>(hbf, csr_src, offsets, dinv, b1, bufA, N, 1);

    // ---- layer 2 ----
    gemm64<<<gemmGrid, 256, 0, stream>>>(bufA, W2, dinv, hbf, N);
    gather_agg<<<gatherGrid, 256, 0, stream>>>(hbf, csr_src, offsets, dinv, b2, bufA, N, 1);

    // ---- layer 3 ----
    gemm64<<<gemmGrid, 256, 0, stream>>>(bufA, W3, dinv, hbf, N);
    gather_agg<<<gatherGrid, 256, 0, stream>>>(hbf, csr_src, offsets, dinv, b3, bufA, N, 0);

    // ---- global mean pool (no atomics) ----
    pool2<<<NGRAPH, 256, 0, stream>>>(bufA, gstart, out);
}

// Round 8
// 337.427 us; speedup vs baseline: 1.5916x; 1.0562x over previous
//
#include <hip/hip_runtime.h>

#define N_NODES 100000
#define N_EDGES 1600000
#define FDIM 64
#define NGRAPH 512
#define NB 782          // dst buckets of 128 nodes
#define NWG 256         // workgroups in hist/bin passes
#define CHUNK 6250      // E / NWG

__device__ __forceinline__ unsigned short f2bf(float v) {
    unsigned int x = __float_as_uint(v);
    x += 0x7FFF + ((x >> 16) & 1);          // RTNE
    return (unsigned short)(x >> 16);
}
__device__ __forceinline__ float bf2f(unsigned short u) {
    return __uint_as_float(((unsigned int)u) << 16);
}

// ================= 3-kernel exclusive scan (generic) =================
__global__ void scan_block(const int* __restrict__ in, int* __restrict__ excl,
                           int* __restrict__ blocksums, int n) {
    __shared__ int lds[256];
    int t = threadIdx.x;
    int base = blockIdx.x * 1024 + t * 4;
    int v0 = (base     < n) ? in[base]     : 0;
    int v1 = (base + 1 < n) ? in[base + 1] : 0;
    int v2 = (base + 2 < n) ? in[base + 2] : 0;
    int v3 = (base + 3 < n) ? in[base + 3] : 0;
    int s = v0 + v1 + v2 + v3;
    lds[t] = s;
    __syncthreads();
    for (int off = 1; off < 256; off <<= 1) {
        int x = (t >= off) ? lds[t - off] : 0;
        __syncthreads();
        lds[t] += x;
        __syncthreads();
    }
    int thrExcl = lds[t] - s;
    if (t == 255) blocksums[blockIdx.x] = lds[255];
    if (base     < n) excl[base]     = thrExcl;
    if (base + 1 < n) excl[base + 1] = thrExcl + v0;
    if (base + 2 < n) excl[base + 2] = thrExcl + v0 + v1;
    if (base + 3 < n) excl[base + 3] = thrExcl + v0 + v1 + v2;
}

__global__ void scan_top(int* __restrict__ blocksums, int nb, int* __restrict__ out, int n) {
    if (threadIdx.x == 0 && blockIdx.x == 0) {
        int run = 0;
        for (int i = 0; i < nb; ++i) { int v = blocksums[i]; blocksums[i] = run; run += v; }
        out[n] = run;
    }
}

__global__ void scan_add(int* __restrict__ out, const int* __restrict__ blocksums, int n) {
    int i = blockIdx.x * blockDim.x + threadIdx.x;
    if (i < n) out[i] += blocksums[i >> 10];
}

// ================= pass A: per-wg bucket histogram =================
__global__ __launch_bounds__(256) void hist_kernel(const int* __restrict__ dst,
                                                   int* __restrict__ hist, int E) {
    __shared__ int h[NB];
    int t = threadIdx.x, wg = blockIdx.x;
    for (int i = t; i < NB; i += 256) h[i] = 0;
    __syncthreads();
    int beg = wg * CHUNK, end = min(beg + CHUNK, E);
    for (int i = beg + t; i < end; i += 256) atomicAdd(&h[dst[i] >> 7], 1);
    __syncthreads();
    for (int i = t; i < NB; i += 256) hist[i * NWG + wg] = h[i];
}

// ================= pass B: binned append (LDS cursors, packed 4B edges) =================
__global__ __launch_bounds__(256) void bin_kernel(const int* __restrict__ src,
                                                  const int* __restrict__ dst,
                                                  const int* __restrict__ scannedH,
                                                  int* __restrict__ ebin, int E) {
    __shared__ int base[NB];
    __shared__ int cur[NB];
    int t = threadIdx.x, wg = blockIdx.x;
    for (int i = t; i < NB; i += 256) { base[i] = scannedH[i * NWG + wg]; cur[i] = 0; }
    __syncthreads();
    int beg = wg * CHUNK, end = min(beg + CHUNK, E);
    for (int i = beg + t; i < end; i += 256) {
        int d = dst[i];
        int b = d >> 7;
        int p = base[b] + atomicAdd(&cur[b], 1);
        ebin[p] = ((d & 127) << 17) | src[i];
    }
}

// ================= pass C: per-bucket sort + degree + dinv + offsets =================
__global__ __launch_bounds__(256) void csr_sort2(const int* __restrict__ ebin,
                                                 const int* __restrict__ scannedH,
                                                 int* __restrict__ csr_src,
                                                 int* __restrict__ offsets,
                                                 float* __restrict__ dinv, int E) {
    __shared__ int cnt[128];
    __shared__ int seg[128];
    __shared__ int cur[128];
    __shared__ int buf[4352];
    int t = threadIdx.x, b = blockIdx.x;
    int nbase = b << 7;
    int nodes = min(128, N_NODES - nbase);
    int bstart = scannedH[b * NWG];
    int bend = (b == NB - 1) ? E : scannedH[(b + 1) * NWG];
    if (t < 128) cnt[t] = 0;
    __syncthreads();
    for (int i = bstart + t; i < bend; i += 256) atomicAdd(&cnt[ebin[i] >> 17], 1);
    __syncthreads();
    if (t < 128) seg[t] = cnt[t];
    __syncthreads();
    for (int off = 1; off < 128; off <<= 1) {
        int v = 0;
        if (t < 128 && t >= off) v = seg[t - off];
        __syncthreads();
        if (t < 128) seg[t] += v;
        __syncthreads();
    }
    if (t < nodes) {
        int excl = seg[t] - cnt[t];
        offsets[nbase + t] = bstart + excl;
        dinv[nbase + t] = rsqrtf((float)cnt[t] + 1.0f);   // +1 self loop
        cur[t] = excl;
    }
    if (b == 0 && t == 0) offsets[N_NODES] = E;
    __syncthreads();
    for (int i = bstart + t; i < bend; i += 256) {
        int v = ebin[i];
        int p = atomicAdd(&cur[v >> 17], 1);
        buf[p] = v & 0x1FFFF;
    }
    __syncthreads();
    int span = bend - bstart;
    for (int i = t; i < span; i += 256) csr_src[bstart + i] = buf[i];
}

// ================= fp32 GEMM -> bf16 out: Hs = bf16((X @ W) * dinv[row]) =================
__global__ __launch_bounds__(256) void gemm64(const float* __restrict__ X,
                                              const float* __restrict__ W,
                                              const float* __restrict__ dinv,
                                              unsigned short* __restrict__ Hout, int n) {
    __shared__ float Ws[64 * 64];
    __shared__ float Xs[64 * 65];
    int t = threadIdx.x;
    int r0 = blockIdx.x * 64;

    #pragma unroll
    for (int k = 0; k < 16; ++k) Ws[t + k * 256] = W[t + k * 256];

    #pragma unroll
    for (int k = 0; k < 16; ++k) {
        int idx = t + k * 256;
        int row = idx >> 6, col = idx & 63;
        float v = (r0 + row < n) ? X[(size_t)(r0 + row) * FDIM + col] : 0.0f;
        Xs[col * 65 + row] = v;
    }
    __syncthreads();

    int row = t & 63;
    int cg  = (t >> 6) * 16;
    float acc[16];
    #pragma unroll
    for (int j = 0; j < 16; ++j) acc[j] = 0.0f;

    for (int k = 0; k < 64; ++k) {
        float xv = Xs[k * 65 + row];
        #pragma unroll
        for (int j = 0; j < 16; ++j) acc[j] += xv * Ws[k * 64 + cg + j];
    }

    if (r0 + row < n) {
        float sc = dinv[r0 + row];
        unsigned int* o = (unsigned int*)&Hout[(size_t)(r0 + row) * FDIM + cg];
        #pragma unroll
        for (int j = 0; j < 8; ++j) {
            unsigned int lo = f2bf(acc[2 * j]     * sc);
            unsigned int hi = f2bf(acc[2 * j + 1] * sc);
            o[j] = lo | (hi << 16);
        }
    }
}

// ================= gather aggregation, 8 edges/wave-iter over bf16 rows =================
// wave = 1 dst node; lane = (g = lane>>3 edge slot, p = lane&7 feature octet).
// Each lane loads uint4 = 8 bf16 (16 B). Cross-slot reduce via shfl_xor 8/16/32.
__global__ __launch_bounds__(256) void gather_agg8(const unsigned short* __restrict__ hs,
                                                   const int* __restrict__ csr_src,
                                                   const int* __restrict__ offsets,
                                                   const float* __restrict__ dinv,
                                                   const float* __restrict__ bias,
                                                   float* __restrict__ outb,
                                                   int n, int do_relu) {
    int node = blockIdx.x * 4 + (threadIdx.x >> 6);
    int lane = threadIdx.x & 63;
    if (node >= n) return;
    int g = lane >> 3;
    int p = lane & 7;
    int beg = offsets[node], end = offsets[node + 1];

    float a0 = 0, a1 = 0, a2 = 0, a3 = 0, a4 = 0, a5 = 0, a6 = 0, a7 = 0;
    for (int k = beg; k < end; k += 8) {
        int e = k + g;
        if (e < end) {
            int s = csr_src[e];
            uint4 v = *(const uint4*)(hs + ((size_t)s << 6) + (p << 3));
            a0 += bf2f((unsigned short)(v.x & 0xFFFF));
            a1 += bf2f((unsigned short)(v.x >> 16));
            a2 += bf2f((unsigned short)(v.y & 0xFFFF));
            a3 += bf2f((unsigned short)(v.y >> 16));
            a4 += bf2f((unsigned short)(v.z & 0xFFFF));
            a5 += bf2f((unsigned short)(v.z >> 16));
            a6 += bf2f((unsigned short)(v.w & 0xFFFF));
            a7 += bf2f((unsigned short)(v.w >> 16));
        }
    }
    // reduce over the 8 edge slots (lanes differing in bits 3..5)
    #pragma unroll
    for (int m = 8; m < 64; m <<= 1) {
        a0 += __shfl_xor(a0, m, 64);
        a1 += __shfl_xor(a1, m, 64);
        a2 += __shfl_xor(a2, m, 64);
        a3 += __shfl_xor(a3, m, 64);
        a4 += __shfl_xor(a4, m, 64);
        a5 += __shfl_xor(a5, m, 64);
        a6 += __shfl_xor(a6, m, 64);
        a7 += __shfl_xor(a7, m, 64);
    }
    if (g == 0) {
        uint4 sv = *(const uint4*)(hs + ((size_t)node << 6) + (p << 3));
        float dd = dinv[node];
        int fb = p << 3;
        float o0 = dd * (a0 + bf2f((unsigned short)(sv.x & 0xFFFF))) + bias[fb + 0];
        float o1 = dd * (a1 + bf2f((unsigned short)(sv.x >> 16)))    + bias[fb + 1];
        float o2 = dd * (a2 + bf2f((unsigned short)(sv.y & 0xFFFF))) + bias[fb + 2];
        float o3 = dd * (a3 + bf2f((unsigned short)(sv.y >> 16)))    + bias[fb + 3];
        float o4 = dd * (a4 + bf2f((unsigned short)(sv.z & 0xFFFF))) + bias[fb + 4];
        float o5 = dd * (a5 + bf2f((unsigned short)(sv.z >> 16)))    + bias[fb + 5];
        float o6 = dd * (a6 + bf2f((unsigned short)(sv.w & 0xFFFF))) + bias[fb + 6];
        float o7 = dd * (a7 + bf2f((unsigned short)(sv.w >> 16)))    + bias[fb + 7];
        if (do_relu) {
            o0 = fmaxf(o0, 0.0f); o1 = fmaxf(o1, 0.0f); o2 = fmaxf(o2, 0.0f); o3 = fmaxf(o3, 0.0f);
            o4 = fmaxf(o4, 0.0f); o5 = fmaxf(o5, 0.0f); o6 = fmaxf(o6, 0.0f); o7 = fmaxf(o7, 0.0f);
        }
        float4* op = (float4*)(outb + (size_t)node * FDIM + fb);
        op[0] = make_float4(o0, o1, o2, o3);
        op[1] = make_float4(o4, o5, o6, o7);
    }
}

// ================= pooling (batch sorted -> segmented reduction) =================
__global__ void gstart_kernel(const int* __restrict__ batch, int* __restrict__ gstart, int n) {
    int g = blockIdx.x * blockDim.x + threadIdx.x;
    if (g > NGRAPH) return;
    if (g == NGRAPH) { gstart[NGRAPH] = n; return; }
    int lo = 0, hi = n;
    while (lo < hi) {
        int mid = (lo + hi) >> 1;
        if (batch[mid] < g) lo = mid + 1; else hi = mid;
    }
    gstart[g] = lo;
}

__global__ __launch_bounds__(256) void pool2(const float* __restrict__ h,
                                             const int* __restrict__ gstart,
                                             float* __restrict__ out) {
    __shared__ float red[4][64];
    int g = blockIdx.x;
    int beg = gstart[g], end = gstart[g + 1];
    int w = threadIdx.x >> 6, lane = threadIdx.x & 63;
    float acc = 0.0f;
    for (int i = beg + w; i < end; i += 4)
        acc += h[(size_t)i * FDIM + lane];
    red[w][lane] = acc;
    __syncthreads();
    if (w == 0) {
        float tot = red[0][lane] + red[1][lane] + red[2][lane] + red[3][lane];
        float cnt = (float)(end - beg);
        out[(size_t)g * FDIM + lane] = tot / fmaxf(cnt, 1.0f);
    }
}

extern "C" void kernel_launch(void* const* d_in, const int* in_sizes, int n_in,
                              void* d_out, int out_size, void* d_ws, size_t ws_size,
                              hipStream_t stream) {
    const float* x     = (const float*)d_in[0];
    const int*   ei    = (const int*)d_in[1];
    const int*   batch = (const int*)d_in[2];
    const float* W1    = (const float*)d_in[3];
    const float* b1    = (const float*)d_in[4];
    const float* W2    = (const float*)d_in[5];
    const float* b2    = (const float*)d_in[6];
    const float* W3    = (const float*)d_in[7];
    const float* b3    = (const float*)d_in[8];
    float* out = (float*)d_out;

    const int N = N_NODES, E = N_EDGES;
    const int* src = ei;
    const int* dst = ei + E;

    // -------- workspace partition (bytes, 256-aligned) --------
    char* ws = (char*)d_ws;
    float*          dinv    = (float*)         (ws + 0);         //   400000 B
    int*            offsets = (int*)           (ws + 400128);    //   400004 B (N+1)
    int*            csr_src = (int*)           (ws + 800256);    //  6400000 B
    float*          bufA    = (float*)         (ws + 7200384);   // 25600000 B (fp32 gather out / gemm in)
    unsigned short* hbf     = (unsigned short*)(ws + 32800384);  // 12800000 B (bf16 gemm out / gather in)
    int*            gstart  = (int*)           (ws + 45600384);  //     2052 B
    // aliases into bufA (dead before layer kernels):
    int* scannedH   = (int*)(ws + 7200384);            // NB*NWG+1 ints (~801 KB)
    int* blocksumsH = (int*)(ws + 8201216);            // 196 ints
    int* ebin       = (int*)(ws + 8202240);            // E ints (6.4 MB)

    // -------- bucketed counting sort -> CSR + degree/dinv/offsets --------
    hist_kernel<<<NWG, 256, 0, stream>>>(dst, scannedH, E);
    const int nH = NB * NWG;                // 200192
    const int nScanH = (nH + 1023) / 1024;  // 196
    scan_block<<<nScanH, 256, 0, stream>>>(scannedH, scannedH, blocksumsH, nH);
    scan_top<<<1, 64, 0, stream>>>(blocksumsH, nScanH, scannedH, nH);
    scan_add<<<(nH + 255) / 256, 256, 0, stream>>>(scannedH, blocksumsH, nH);
    bin_kernel<<<NWG, 256, 0, stream>>>(src, dst, scannedH, ebin, E);
    csr_sort2<<<NB, 256, 0, stream>>>(ebin, scannedH, csr_src, offsets, dinv, E);

    // -------- graph boundaries (batch sorted) --------
    gstart_kernel<<<3, 256, 0, stream>>>(batch, gstart, N);

    const int gemmGrid   = (N + 63) / 64;
    const int gatherGrid = (N + 3) / 4;

    // ---- layer 1 ----  (gemm prescales by dinv, outputs bf16; gather accumulates fp32)
    gemm64<<<gemmGrid, 256, 0, stream>>>(x, W1, dinv, hbf, N);
    gather_agg8<<<gatherGrid, 256, 0, stream>>>(hbf, csr_src, offsets, dinv, b1, bufA, N, 1);

    // ---- layer 2 ----
    gemm64<<<gemmGrid, 256, 0, stream>>>(bufA, W2, dinv, hbf, N);
    gather_agg8<<<gatherGrid, 256, 0, stream>>>(hbf, csr_src, offsets, dinv, b2, bufA, N, 1);

    // ---- layer 3 ----
    gemm64<<<gemmGrid, 256, 0, stream>>>(bufA, W3, dinv, hbf, N);
    gather_agg8<<<gatherGrid, 256, 0, stream>>>(hbf, csr_src, offsets, dinv, b3, bufA, N, 0);

    // ---- global mean pool (no atomics) ----
    pool2<<<NGRAPH, 256, 0, stream>>>(bufA, gstart, out);
}

// Round 9
// 316.765 us; speedup vs baseline: 1.6954x; 1.0652x over previous
//
#include <hip/hip_runtime.h>

#define N_NODES 100000
#define N_EDGES 1600000
#define FDIM 64
#define NGRAPH 512
#define NB 782          // dst buckets of 128 nodes
#define NWG 256         // workgroups in hist/bin passes
#define CHUNK 6250      // E / NWG
#define DWG 64          // workgroups for degree binning
#define DCHUNK ((N_NODES + DWG - 1) / DWG)
#define MAXD 128        // degree clamp for counting sort

__device__ __forceinline__ unsigned short f2bf(float v) {
    unsigned int x = __float_as_uint(v);
    x += 0x7FFF + ((x >> 16) & 1);          // RTNE
    return (unsigned short)(x >> 16);
}

// ================= 3-kernel exclusive scan (generic) =================
__global__ void scan_block(const int* __restrict__ in, int* __restrict__ excl,
                           int* __restrict__ blocksums, int n) {
    __shared__ int lds[256];
    int t = threadIdx.x;
    int base = blockIdx.x * 1024 + t * 4;
    int v0 = (base     < n) ? in[base]     : 0;
    int v1 = (base + 1 < n) ? in[base + 1] : 0;
    int v2 = (base + 2 < n) ? in[base + 2] : 0;
    int v3 = (base + 3 < n) ? in[base + 3] : 0;
    int s = v0 + v1 + v2 + v3;
    lds[t] = s;
    __syncthreads();
    for (int off = 1; off < 256; off <<= 1) {
        int x = (t >= off) ? lds[t - off] : 0;
        __syncthreads();
        lds[t] += x;
        __syncthreads();
    }
    int thrExcl = lds[t] - s;
    if (t == 255) blocksums[blockIdx.x] = lds[255];
    if (base     < n) excl[base]     = thrExcl;
    if (base + 1 < n) excl[base + 1] = thrExcl + v0;
    if (base + 2 < n) excl[base + 2] = thrExcl + v0 + v1;
    if (base + 3 < n) excl[base + 3] = thrExcl + v0 + v1 + v2;
}

__global__ void scan_top(int* __restrict__ blocksums, int nb, int* __restrict__ out, int n) {
    if (threadIdx.x == 0 && blockIdx.x == 0) {
        int run = 0;
        for (int i = 0; i < nb; ++i) { int v = blocksums[i]; blocksums[i] = run; run += v; }
        out[n] = run;
    }
}

__global__ void scan_add(int* __restrict__ out, const int* __restrict__ blocksums, int n) {
    int i = blockIdx.x * blockDim.x + threadIdx.x;
    if (i < n) out[i] += blocksums[i >> 10];
}

// ================= pass A: per-wg bucket histogram =================
__global__ __launch_bounds__(256) void hist_kernel(const int* __restrict__ dst,
                                                   int* __restrict__ hist, int E) {
    __shared__ int h[NB];
    int t = threadIdx.x, wg = blockIdx.x;
    for (int i = t; i < NB; i += 256) h[i] = 0;
    __syncthreads();
    int beg = wg * CHUNK, end = min(beg + CHUNK, E);
    for (int i = beg + t; i < end; i += 256) atomicAdd(&h[dst[i] >> 7], 1);
    __syncthreads();
    for (int i = t; i < NB; i += 256) hist[i * NWG + wg] = h[i];
}

// ================= pass B: binned append (LDS cursors, packed 4B edges) =================
__global__ __launch_bounds__(256) void bin_kernel(const int* __restrict__ src,
                                                  const int* __restrict__ dst,
                                                  const int* __restrict__ scannedH,
                                                  int* __restrict__ ebin, int E) {
    __shared__ int base[NB];
    __shared__ int cur[NB];
    int t = threadIdx.x, wg = blockIdx.x;
    for (int i = t; i < NB; i += 256) { base[i] = scannedH[i * NWG + wg]; cur[i] = 0; }
    __syncthreads();
    int beg = wg * CHUNK, end = min(beg + CHUNK, E);
    for (int i = beg + t; i < end; i += 256) {
        int d = dst[i];
        int b = d >> 7;
        int p = base[b] + atomicAdd(&cur[b], 1);
        ebin[p] = ((d & 127) << 17) | src[i];
    }
}

// ================= pass C: per-bucket sort + degree + dinv + offsets =================
__global__ __launch_bounds__(256) void csr_sort2(const int* __restrict__ ebin,
                                                 const int* __restrict__ scannedH,
                                                 int* __restrict__ csr_src,
                                                 int* __restrict__ offsets,
                                                 float* __restrict__ dinv, int E) {
    __shared__ int cnt[128];
    __shared__ int seg[128];
    __shared__ int cur[128];
    __shared__ int buf[4352];
    int t = threadIdx.x, b = blockIdx.x;
    int nbase = b << 7;
    int nodes = min(128, N_NODES - nbase);
    int bstart = scannedH[b * NWG];
    int bend = (b == NB - 1) ? E : scannedH[(b + 1) * NWG];
    if (t < 128) cnt[t] = 0;
    __syncthreads();
    for (int i = bstart + t; i < bend; i += 256) atomicAdd(&cnt[ebin[i] >> 17], 1);
    __syncthreads();
    if (t < 128) seg[t] = cnt[t];
    __syncthreads();
    for (int off = 1; off < 128; off <<= 1) {
        int v = 0;
        if (t < 128 && t >= off) v = seg[t - off];
        __syncthreads();
        if (t < 128) seg[t] += v;
        __syncthreads();
    }
    if (t < nodes) {
        int excl = seg[t] - cnt[t];
        offsets[nbase + t] = bstart + excl;
        dinv[nbase + t] = rsqrtf((float)cnt[t] + 1.0f);   // +1 self loop
        cur[t] = excl;
    }
    if (b == 0 && t == 0) offsets[N_NODES] = E;
    __syncthreads();
    for (int i = bstart + t; i < bend; i += 256) {
        int v = ebin[i];
        int p = atomicAdd(&cur[v >> 17], 1);
        buf[p] = v & 0x1FFFF;
    }
    __syncthreads();
    int span = bend - bstart;
    for (int i = t; i < span; i += 256) csr_src[bstart + i] = buf[i];
}

// ================= degree counting sort: nodes grouped by degree =================
__global__ __launch_bounds__(256) void histD_kernel(const int* __restrict__ offsets,
                                                    int* __restrict__ histD) {
    __shared__ int h[MAXD];
    int t = threadIdx.x, wg = blockIdx.x;
    if (t < MAXD) h[t] = 0;
    __syncthreads();
    int beg = wg * DCHUNK, end = min(beg + DCHUNK, N_NODES);
    for (int i = beg + t; i < end; i += 256) {
        int d = min(offsets[i + 1] - offsets[i], MAXD - 1);
        atomicAdd(&h[d], 1);
    }
    __syncthreads();
    if (t < MAXD) histD[t * DWG + wg] = h[t];
}

__global__ __launch_bounds__(256) void binD_kernel(const int* __restrict__ offsets,
                                                   const int* __restrict__ scannedD,
                                                   int* __restrict__ perm) {
    __shared__ int base[MAXD];
    __shared__ int cur[MAXD];
    int t = threadIdx.x, wg = blockIdx.x;
    if (t < MAXD) { base[t] = scannedD[t * DWG + wg]; cur[t] = 0; }
    __syncthreads();
    int beg = wg * DCHUNK, end = min(beg + DCHUNK, N_NODES);
    for (int i = beg + t; i < end; i += 256) {
        int d = min(offsets[i + 1] - offsets[i], MAXD - 1);
        int pos = base[d] + atomicAdd(&cur[d], 1);
        perm[pos] = i;
    }
}

// ================= fp32 GEMM -> bf16 out: Hs = bf16((X @ W) * dinv[row]) =================
__global__ __launch_bounds__(256) void gemm64(const float* __restrict__ X,
                                              const float* __restrict__ W,
                                              const float* __restrict__ dinv,
                                              unsigned short* __restrict__ Hout, int n) {
    __shared__ float Ws[64 * 64];
    __shared__ float Xs[64 * 65];
    int t = threadIdx.x;
    int r0 = blockIdx.x * 64;

    #pragma unroll
    for (int k = 0; k < 16; ++k) Ws[t + k * 256] = W[t + k * 256];

    #pragma unroll
    for (int k = 0; k < 16; ++k) {
        int idx = t + k * 256;
        int row = idx >> 6, col = idx & 63;
        float v = (r0 + row < n) ? X[(size_t)(r0 + row) * FDIM + col] : 0.0f;
        Xs[col * 65 + row] = v;
    }
    __syncthreads();

    int row = t & 63;
    int cg  = (t >> 6) * 16;
    float acc[16];
    #pragma unroll
    for (int j = 0; j < 16; ++j) acc[j] = 0.0f;

    for (int k = 0; k < 64; ++k) {
        float xv = Xs[k * 65 + row];
        #pragma unroll
        for (int j = 0; j < 16; ++j) acc[j] += xv * Ws[k * 64 + cg + j];
    }

    if (r0 + row < n) {
        float sc = dinv[r0 + row];
        unsigned int* o = (unsigned int*)&Hout[(size_t)(r0 + row) * FDIM + cg];
        #pragma unroll
        for (int j = 0; j < 8; ++j) {
            unsigned int lo = f2bf(acc[2 * j]     * sc);
            unsigned int hi = f2bf(acc[2 * j + 1] * sc);
            o[j] = lo | (hi << 16);
        }
    }
}

// ================= gather, 8 lanes own one node (no cross-lane reduce) =================
// slot = 8-lane group processes node perm[slot]; lane p = feature octet, uint4 = 8 bf16.
__global__ __launch_bounds__(256) void gather_pn(const unsigned short* __restrict__ hs,
                                                 const int* __restrict__ csr_src,
                                                 const int* __restrict__ offsets,
                                                 const int* __restrict__ perm,
                                                 const float* __restrict__ dinv,
                                                 const float* __restrict__ bias,
                                                 float* __restrict__ outb,
                                                 int n, int do_relu) {
    int slot = (blockIdx.x * 256 + threadIdx.x) >> 3;
    int p = threadIdx.x & 7;
    if (slot >= n) return;
    int node = perm[slot];
    int beg = offsets[node], end = offsets[node + 1];

    float a0 = 0, a1 = 0, a2 = 0, a3 = 0, a4 = 0, a5 = 0, a6 = 0, a7 = 0;
    int k = beg;
    for (; k + 1 < end; k += 2) {
        int s0 = csr_src[k], s1 = csr_src[k + 1];
        uint4 v0 = *(const uint4*)(hs + ((size_t)s0 << 6) + (p << 3));
        uint4 v1 = *(const uint4*)(hs + ((size_t)s1 << 6) + (p << 3));
        a0 += __uint_as_float(v0.x << 16); a1 += __uint_as_float(v0.x & 0xFFFF0000u);
        a2 += __uint_as_float(v0.y << 16); a3 += __uint_as_float(v0.y & 0xFFFF0000u);
        a4 += __uint_as_float(v0.z << 16); a5 += __uint_as_float(v0.z & 0xFFFF0000u);
        a6 += __uint_as_float(v0.w << 16); a7 += __uint_as_float(v0.w & 0xFFFF0000u);
        a0 += __uint_as_float(v1.x << 16); a1 += __uint_as_float(v1.x & 0xFFFF0000u);
        a2 += __uint_as_float(v1.y << 16); a3 += __uint_as_float(v1.y & 0xFFFF0000u);
        a4 += __uint_as_float(v1.z << 16); a5 += __uint_as_float(v1.z & 0xFFFF0000u);
        a6 += __uint_as_float(v1.w << 16); a7 += __uint_as_float(v1.w & 0xFFFF0000u);
    }
    if (k < end) {
        int s0 = csr_src[k];
        uint4 v0 = *(const uint4*)(hs + ((size_t)s0 << 6) + (p << 3));
        a0 += __uint_as_float(v0.x << 16); a1 += __uint_as_float(v0.x & 0xFFFF0000u);
        a2 += __uint_as_float(v0.y << 16); a3 += __uint_as_float(v0.y & 0xFFFF0000u);
        a4 += __uint_as_float(v0.z << 16); a5 += __uint_as_float(v0.z & 0xFFFF0000u);
        a6 += __uint_as_float(v0.w << 16); a7 += __uint_as_float(v0.w & 0xFFFF0000u);
    }
    // self-loop row
    uint4 sv = *(const uint4*)(hs + ((size_t)node << 6) + (p << 3));
    float dd = dinv[node];
    int fb = p << 3;
    const float4* bp = (const float4*)(bias + fb);
    float4 bv0 = bp[0], bv1 = bp[1];
    float o0 = dd * (a0 + __uint_as_float(sv.x << 16))        + bv0.x;
    float o1 = dd * (a1 + __uint_as_float(sv.x & 0xFFFF0000u)) + bv0.y;
    float o2 = dd * (a2 + __uint_as_float(sv.y << 16))        + bv0.z;
    float o3 = dd * (a3 + __uint_as_float(sv.y & 0xFFFF0000u)) + bv0.w;
    float o4 = dd * (a4 + __uint_as_float(sv.z << 16))        + bv1.x;
    float o5 = dd * (a5 + __uint_as_float(sv.z & 0xFFFF0000u)) + bv1.y;
    float o6 = dd * (a6 + __uint_as_float(sv.w << 16))        + bv1.z;
    float o7 = dd * (a7 + __uint_as_float(sv.w & 0xFFFF0000u)) + bv1.w;
    if (do_relu) {
        o0 = fmaxf(o0, 0.0f); o1 = fmaxf(o1, 0.0f); o2 = fmaxf(o2, 0.0f); o3 = fmaxf(o3, 0.0f);
        o4 = fmaxf(o4, 0.0f); o5 = fmaxf(o5, 0.0f); o6 = fmaxf(o6, 0.0f); o7 = fmaxf(o7, 0.0f);
    }
    float4* op = (float4*)(outb + (size_t)node * FDIM + fb);
    op[0] = make_float4(o0, o1, o2, o3);
    op[1] = make_float4(o4, o5, o6, o7);
}

// ================= pooling (batch sorted -> segmented reduction) =================
__global__ void gstart_kernel(const int* __restrict__ batch, int* __restrict__ gstart, int n) {
    int g = blockIdx.x * blockDim.x + threadIdx.x;
    if (g > NGRAPH) return;
    if (g == NGRAPH) { gstart[NGRAPH] = n; return; }
    int lo = 0, hi = n;
    while (lo < hi) {
        int mid = (lo + hi) >> 1;
        if (batch[mid] < g) lo = mid + 1; else hi = mid;
    }
    gstart[g] = lo;
}

__global__ __launch_bounds__(256) void pool2(const float* __restrict__ h,
                                             const int* __restrict__ gstart,
                                             float* __restrict__ out) {
    __shared__ float red[4][64];
    int g = blockIdx.x;
    int beg = gstart[g], end = gstart[g + 1];
    int w = threadIdx.x >> 6, lane = threadIdx.x & 63;
    float acc = 0.0f;
    for (int i = beg + w; i < end; i += 4)
        acc += h[(size_t)i * FDIM + lane];
    red[w][lane] = acc;
    __syncthreads();
    if (w == 0) {
        float tot = red[0][lane] + red[1][lane] + red[2][lane] + red[3][lane];
        float cnt = (float)(end - beg);
        out[(size_t)g * FDIM + lane] = tot / fmaxf(cnt, 1.0f);
    }
}

extern "C" void kernel_launch(void* const* d_in, const int* in_sizes, int n_in,
                              void* d_out, int out_size, void* d_ws, size_t ws_size,
                              hipStream_t stream) {
    const float* x     = (const float*)d_in[0];
    const int*   ei    = (const int*)d_in[1];
    const int*   batch = (const int*)d_in[2];
    const float* W1    = (const float*)d_in[3];
    const float* b1    = (const float*)d_in[4];
    const float* W2    = (const float*)d_in[5];
    const float* b2    = (const float*)d_in[6];
    const float* W3    = (const float*)d_in[7];
    const float* b3    = (const float*)d_in[8];
    float* out = (float*)d_out;

    const int N = N_NODES, E = N_EDGES;
    const int* src = ei;
    const int* dst = ei + E;

    // -------- workspace partition (bytes, 256-aligned) --------
    char* ws = (char*)d_ws;
    float*          dinv    = (float*)         (ws + 0);         //   400000 B
    int*            offsets = (int*)           (ws + 400128);    //   400004 B (N+1)
    int*            csr_src = (int*)           (ws + 800256);    //  6400000 B
    float*          bufA    = (float*)         (ws + 7200384);   // 25600000 B (fp32 gather out / gemm in)
    unsigned short* hbf     = (unsigned short*)(ws + 32800384);  // 12800000 B (bf16 gemm out / gather in)
    int*            gstart  = (int*)           (ws + 45600384);  //     2052 B
    int*            perm    = (int*)           (ws + 45602560);  //   400000 B
    int*            scannedD= (int*)           (ws + 46002688);  //    32772 B (MAXD*DWG+1)
    int*            blocksumsD=(int*)          (ws + 46035584);  //      512 B
    // aliases into bufA (dead before layer kernels):
    int* scannedH   = (int*)(ws + 7200384);            // NB*NWG+1 ints (~801 KB)
    int* blocksumsH = (int*)(ws + 8201216);            // 196 ints
    int* ebin       = (int*)(ws + 8202240);            // E ints (6.4 MB)

    // -------- bucketed counting sort -> CSR + degree/dinv/offsets --------
    hist_kernel<<<NWG, 256, 0, stream>>>(dst, scannedH, E);
    const int nH = NB * NWG;                // 200192
    const int nScanH = (nH + 1023) / 1024;  // 196
    scan_block<<<nScanH, 256, 0, stream>>>(scannedH, scannedH, blocksumsH, nH);
    scan_top<<<1, 64, 0, stream>>>(blocksumsH, nScanH, scannedH, nH);
    scan_add<<<(nH + 255) / 256, 256, 0, stream>>>(scannedH, blocksumsH, nH);
    bin_kernel<<<NWG, 256, 0, stream>>>(src, dst, scannedH, ebin, E);
    csr_sort2<<<NB, 256, 0, stream>>>(ebin, scannedH, csr_src, offsets, dinv, E);

    // -------- degree-sorted node permutation --------
    histD_kernel<<<DWG, 256, 0, stream>>>(offsets, scannedD);
    const int nD = MAXD * DWG;              // 8192
    const int nScanD = (nD + 1023) / 1024;  // 8
    scan_block<<<nScanD, 256, 0, stream>>>(scannedD, scannedD, blocksumsD, nD);
    scan_top<<<1, 64, 0, stream>>>(blocksumsD, nScanD, scannedD, nD);
    scan_add<<<(nD + 255) / 256, 256, 0, stream>>>(scannedD, blocksumsD, nD);
    binD_kernel<<<DWG, 256, 0, stream>>>(offsets, scannedD, perm);

    // -------- graph boundaries (batch sorted) --------
    gstart_kernel<<<3, 256, 0, stream>>>(batch, gstart, N);

    const int gemmGrid   = (N + 63) / 64;
    const int gatherGrid = (N * 8 + 255) / 256;   // 8 lanes per node

    // ---- layer 1 ----  (gemm prescales by dinv, outputs bf16; gather accumulates fp32)
    gemm64<<<gemmGrid, 256, 0, stream>>>(x, W1, dinv, hbf, N);
    gather_pn<<<gatherGrid, 256, 0, stream>>>(hbf, csr_src, offsets, perm, dinv, b1, bufA, N, 1);

    // ---- layer 2 ----
    gemm64<<<gemmGrid, 256, 0, stream>>>(bufA, W2, dinv, hbf, N);
    gather_pn<<<gatherGrid, 256, 0, stream>>>(hbf, csr_src, offsets, perm, dinv, b2, bufA, N, 1);

    // ---- layer 3 ----
    gemm64<<<gemmGrid, 256, 0, stream>>>(bufA, W3, dinv, hbf, N);
    gather_pn<<<gatherGrid, 256, 0, stream>>>(hbf, csr_src, offsets, perm, dinv, b3, bufA, N, 0);

    // ---- global mean pool (no atomics) ----
    pool2<<<NGRAPH, 256, 0, stream>>>(bufA, gstart, out);
}

// Round 10
// 287.138 us; speedup vs baseline: 1.8703x; 1.1032x over previous
//
#include <hip/hip_runtime.h>

#define N_NODES 100000
#define N_EDGES 1600000
#define FDIM 64
#define NGRAPH 512
#define NB 782          // dst buckets of 128 nodes
#define NWG 256         // workgroups in hist/bin passes
#define CHUNK 6250      // E / NWG
#define DWG 64          // workgroups for degree binning
#define DCHUNK ((N_NODES + DWG - 1) / DWG)
#define MAXD 128        // degree clamp for counting sort

__device__ __forceinline__ unsigned short f2bf(float v) {
    unsigned int x = __float_as_uint(v);
    x += 0x7FFF + ((x >> 16) & 1);          // RTNE
    return (unsigned short)(x >> 16);
}

// ================= 3-kernel exclusive scan (generic) =================
__global__ void scan_block(const int* __restrict__ in, int* __restrict__ excl,
                           int* __restrict__ blocksums, int n) {
    __shared__ int lds[256];
    int t = threadIdx.x;
    int base = blockIdx.x * 1024 + t * 4;
    int v0 = (base     < n) ? in[base]     : 0;
    int v1 = (base + 1 < n) ? in[base + 1] : 0;
    int v2 = (base + 2 < n) ? in[base + 2] : 0;
    int v3 = (base + 3 < n) ? in[base + 3] : 0;
    int s = v0 + v1 + v2 + v3;
    lds[t] = s;
    __syncthreads();
    for (int off = 1; off < 256; off <<= 1) {
        int x = (t >= off) ? lds[t - off] : 0;
        __syncthreads();
        lds[t] += x;
        __syncthreads();
    }
    int thrExcl = lds[t] - s;
    if (t == 255) blocksums[blockIdx.x] = lds[255];
    if (base     < n) excl[base]     = thrExcl;
    if (base + 1 < n) excl[base + 1] = thrExcl + v0;
    if (base + 2 < n) excl[base + 2] = thrExcl + v0 + v1;
    if (base + 3 < n) excl[base + 3] = thrExcl + v0 + v1 + v2;
}

__global__ void scan_top(int* __restrict__ blocksums, int nb, int* __restrict__ out, int n) {
    if (threadIdx.x == 0 && blockIdx.x == 0) {
        int run = 0;
        for (int i = 0; i < nb; ++i) { int v = blocksums[i]; blocksums[i] = run; run += v; }
        out[n] = run;
    }
}

__global__ void scan_add(int* __restrict__ out, const int* __restrict__ blocksums, int n) {
    int i = blockIdx.x * blockDim.x + threadIdx.x;
    if (i < n) out[i] += blocksums[i >> 10];
}

// ================= pass A: per-wg bucket histogram =================
__global__ __launch_bounds__(256) void hist_kernel(const int* __restrict__ dst,
                                                   int* __restrict__ hist, int E) {
    __shared__ int h[NB];
    int t = threadIdx.x, wg = blockIdx.x;
    for (int i = t; i < NB; i += 256) h[i] = 0;
    __syncthreads();
    int beg = wg * CHUNK, end = min(beg + CHUNK, E);
    for (int i = beg + t; i < end; i += 256) atomicAdd(&h[dst[i] >> 7], 1);
    __syncthreads();
    for (int i = t; i < NB; i += 256) hist[i * NWG + wg] = h[i];
}

// ================= pass B: binned append (LDS cursors, packed 4B edges) =================
__global__ __launch_bounds__(256) void bin_kernel(const int* __restrict__ src,
                                                  const int* __restrict__ dst,
                                                  const int* __restrict__ scannedH,
                                                  int* __restrict__ ebin, int E) {
    __shared__ int base[NB];
    __shared__ int cur[NB];
    int t = threadIdx.x, wg = blockIdx.x;
    for (int i = t; i < NB; i += 256) { base[i] = scannedH[i * NWG + wg]; cur[i] = 0; }
    __syncthreads();
    int beg = wg * CHUNK, end = min(beg + CHUNK, E);
    for (int i = beg + t; i < end; i += 256) {
        int d = dst[i];
        int b = d >> 7;
        int p = base[b] + atomicAdd(&cur[b], 1);
        ebin[p] = ((d & 127) << 17) | src[i];
    }
}

// ================= pass C: per-bucket sort + degree + dinv + offsets =================
__global__ __launch_bounds__(256) void csr_sort2(const int* __restrict__ ebin,
                                                 const int* __restrict__ scannedH,
                                                 int* __restrict__ csr_src,
                                                 int* __restrict__ offsets,
                                                 float* __restrict__ dinv, int E) {
    __shared__ int cnt[128];
    __shared__ int seg[128];
    __shared__ int cur[128];
    __shared__ int buf[4352];
    int t = threadIdx.x, b = blockIdx.x;
    int nbase = b << 7;
    int nodes = min(128, N_NODES - nbase);
    int bstart = scannedH[b * NWG];
    int bend = (b == NB - 1) ? E : scannedH[(b + 1) * NWG];
    if (t < 128) cnt[t] = 0;
    __syncthreads();
    for (int i = bstart + t; i < bend; i += 256) atomicAdd(&cnt[ebin[i] >> 17], 1);
    __syncthreads();
    if (t < 128) seg[t] = cnt[t];
    __syncthreads();
    for (int off = 1; off < 128; off <<= 1) {
        int v = 0;
        if (t < 128 && t >= off) v = seg[t - off];
        __syncthreads();
        if (t < 128) seg[t] += v;
        __syncthreads();
    }
    if (t < nodes) {
        int excl = seg[t] - cnt[t];
        offsets[nbase + t] = bstart + excl;
        dinv[nbase + t] = rsqrtf((float)cnt[t] + 1.0f);   // +1 self loop
        cur[t] = excl;
    }
    if (b == 0 && t == 0) offsets[N_NODES] = E;
    __syncthreads();
    for (int i = bstart + t; i < bend; i += 256) {
        int v = ebin[i];
        int p = atomicAdd(&cur[v >> 17], 1);
        buf[p] = v & 0x1FFFF;
    }
    __syncthreads();
    int span = bend - bstart;
    for (int i = t; i < span; i += 256) csr_src[bstart + i] = buf[i];
}

// ================= degree counting sort: nodes grouped by degree =================
__global__ __launch_bounds__(256) void histD_kernel(const int* __restrict__ offsets,
                                                    int* __restrict__ histD) {
    __shared__ int h[MAXD];
    int t = threadIdx.x, wg = blockIdx.x;
    if (t < MAXD) h[t] = 0;
    __syncthreads();
    int beg = wg * DCHUNK, end = min(beg + DCHUNK, N_NODES);
    for (int i = beg + t; i < end; i += 256) {
        int d = min(offsets[i + 1] - offsets[i], MAXD - 1);
        atomicAdd(&h[d], 1);
    }
    __syncthreads();
    if (t < MAXD) histD[t * DWG + wg] = h[t];
}

__global__ __launch_bounds__(256) void binD_kernel(const int* __restrict__ offsets,
                                                   const int* __restrict__ scannedD,
                                                   int* __restrict__ perm) {
    __shared__ int base[MAXD];
    __shared__ int cur[MAXD];
    int t = threadIdx.x, wg = blockIdx.x;
    if (t < MAXD) { base[t] = scannedD[t * DWG + wg]; cur[t] = 0; }
    __syncthreads();
    int beg = wg * DCHUNK, end = min(beg + DCHUNK, N_NODES);
    for (int i = beg + t; i < end; i += 256) {
        int d = min(offsets[i + 1] - offsets[i], MAXD - 1);
        int pos = base[d] + atomicAdd(&cur[d], 1);
        perm[pos] = i;
    }
}

// ================= fp32 GEMM (register-tiled 4x4) -> bf16: Hs = bf16((X@W)*dinv) ======
// block = 256 threads: 16 rowgroups x 16 colgroups, each thread 4 rows x 4 cols.
// LDS: Xs[k][row] pitch 68, Ws[k][col] pitch 68 -> all compute reads are ds_read_b128.
__global__ __launch_bounds__(256) void gemm64(const float* __restrict__ X,
                                              const float* __restrict__ W,
                                              const float* __restrict__ dinv,
                                              unsigned short* __restrict__ Hout, int n) {
    __shared__ float Ws[64 * 68];
    __shared__ float Xs[64 * 68];
    int t = threadIdx.x;
    int r0 = blockIdx.x * 64;

    #pragma unroll
    for (int kk = 0; kk < 16; ++kk) {
        int idx = t + kk * 256;          // 0..4095
        int r = idx >> 6, c = idx & 63;
        Ws[r * 68 + c] = W[idx];         // Ws[k][col]
        float v = (r0 + r < n) ? X[(size_t)(r0 + r) * FDIM + c] : 0.0f;
        Xs[c * 68 + r] = v;              // Xs[k][row] (transposed)
    }
    __syncthreads();

    int rg = (t >> 4) << 2;              // row offset in tile: 0,4,..,60
    int cg = (t & 15) << 2;              // col offset: 0,4,..,60
    float4 acc0 = {0, 0, 0, 0}, acc1 = {0, 0, 0, 0};
    float4 acc2 = {0, 0, 0, 0}, acc3 = {0, 0, 0, 0};

    #pragma unroll 8
    for (int k = 0; k < 64; ++k) {
        float4 xv = *(const float4*)&Xs[k * 68 + rg];
        float4 wv = *(const float4*)&Ws[k * 68 + cg];
        acc0.x += xv.x * wv.x; acc0.y += xv.x * wv.y; acc0.z += xv.x * wv.z; acc0.w += xv.x * wv.w;
        acc1.x += xv.y * wv.x; acc1.y += xv.y * wv.y; acc1.z += xv.y * wv.z; acc1.w += xv.y * wv.w;
        acc2.x += xv.z * wv.x; acc2.y += xv.z * wv.y; acc2.z += xv.z * wv.z; acc2.w += xv.z * wv.w;
        acc3.x += xv.w * wv.x; acc3.y += xv.w * wv.y; acc3.z += xv.w * wv.z; acc3.w += xv.w * wv.w;
    }

    float4 accs[4] = {acc0, acc1, acc2, acc3};
    #pragma unroll
    for (int i = 0; i < 4; ++i) {
        int row = r0 + rg + i;
        if (row < n) {
            float sc = dinv[row];
            unsigned int u0 = (unsigned int)f2bf(accs[i].x * sc) | ((unsigned int)f2bf(accs[i].y * sc) << 16);
            unsigned int u1 = (unsigned int)f2bf(accs[i].z * sc) | ((unsigned int)f2bf(accs[i].w * sc) << 16);
            *(uint2*)&Hout[(size_t)row * FDIM + cg] = make_uint2(u0, u1);
        }
    }
}

// ================= gather, 8 lanes own one node (no cross-lane reduce) =================
// slot = 8-lane group processes node perm[slot]; lane p = feature octet, uint4 = 8 bf16.
__global__ __launch_bounds__(256) void gather_pn(const unsigned short* __restrict__ hs,
                                                 const int* __restrict__ csr_src,
                                                 const int* __restrict__ offsets,
                                                 const int* __restrict__ perm,
                                                 const float* __restrict__ dinv,
                                                 const float* __restrict__ bias,
                                                 float* __restrict__ outb,
                                                 int n, int do_relu) {
    int slot = (blockIdx.x * 256 + threadIdx.x) >> 3;
    int p = threadIdx.x & 7;
    if (slot >= n) return;
    int node = perm[slot];
    int beg = offsets[node], end = offsets[node + 1];

    float a0 = 0, a1 = 0, a2 = 0, a3 = 0, a4 = 0, a5 = 0, a6 = 0, a7 = 0;
    int k = beg;
    for (; k + 1 < end; k += 2) {
        int s0 = csr_src[k], s1 = csr_src[k + 1];
        uint4 v0 = *(const uint4*)(hs + ((size_t)s0 << 6) + (p << 3));
        uint4 v1 = *(const uint4*)(hs + ((size_t)s1 << 6) + (p << 3));
        a0 += __uint_as_float(v0.x << 16); a1 += __uint_as_float(v0.x & 0xFFFF0000u);
        a2 += __uint_as_float(v0.y << 16); a3 += __uint_as_float(v0.y & 0xFFFF0000u);
        a4 += __uint_as_float(v0.z << 16); a5 += __uint_as_float(v0.z & 0xFFFF0000u);
        a6 += __uint_as_float(v0.w << 16); a7 += __uint_as_float(v0.w & 0xFFFF0000u);
        a0 += __uint_as_float(v1.x << 16); a1 += __uint_as_float(v1.x & 0xFFFF0000u);
        a2 += __uint_as_float(v1.y << 16); a3 += __uint_as_float(v1.y & 0xFFFF0000u);
        a4 += __uint_as_float(v1.z << 16); a5 += __uint_as_float(v1.z & 0xFFFF0000u);
        a6 += __uint_as_float(v1.w << 16); a7 += __uint_as_float(v1.w & 0xFFFF0000u);
    }
    if (k < end) {
        int s0 = csr_src[k];
        uint4 v0 = *(const uint4*)(hs + ((size_t)s0 << 6) + (p << 3));
        a0 += __uint_as_float(v0.x << 16); a1 += __uint_as_float(v0.x & 0xFFFF0000u);
        a2 += __uint_as_float(v0.y << 16); a3 += __uint_as_float(v0.y & 0xFFFF0000u);
        a4 += __uint_as_float(v0.z << 16); a5 += __uint_as_float(v0.z & 0xFFFF0000u);
        a6 += __uint_as_float(v0.w << 16); a7 += __uint_as_float(v0.w & 0xFFFF0000u);
    }
    // self-loop row
    uint4 sv = *(const uint4*)(hs + ((size_t)node << 6) + (p << 3));
    float dd = dinv[node];
    int fb = p << 3;
    const float4* bp = (const float4*)(bias + fb);
    float4 bv0 = bp[0], bv1 = bp[1];
    float o0 = dd * (a0 + __uint_as_float(sv.x << 16))        + bv0.x;
    float o1 = dd * (a1 + __uint_as_float(sv.x & 0xFFFF0000u)) + bv0.y;
    float o2 = dd * (a2 + __uint_as_float(sv.y << 16))        + bv0.z;
    float o3 = dd * (a3 + __uint_as_float(sv.y & 0xFFFF0000u)) + bv0.w;
    float o4 = dd * (a4 + __uint_as_float(sv.z << 16))        + bv1.x;
    float o5 = dd * (a5 + __uint_as_float(sv.z & 0xFFFF0000u)) + bv1.y;
    float o6 = dd * (a6 + __uint_as_float(sv.w << 16))        + bv1.z;
    float o7 = dd * (a7 + __uint_as_float(sv.w & 0xFFFF0000u)) + bv1.w;
    if (do_relu) {
        o0 = fmaxf(o0, 0.0f); o1 = fmaxf(o1, 0.0f); o2 = fmaxf(o2, 0.0f); o3 = fmaxf(o3, 0.0f);
        o4 = fmaxf(o4, 0.0f); o5 = fmaxf(o5, 0.0f); o6 = fmaxf(o6, 0.0f); o7 = fmaxf(o7, 0.0f);
    }
    float4* op = (float4*)(outb + (size_t)node * FDIM + fb);
    op[0] = make_float4(o0, o1, o2, o3);
    op[1] = make_float4(o4, o5, o6, o7);
}

// ================= pooling (batch sorted -> segmented reduction) =================
__global__ void gstart_kernel(const int* __restrict__ batch, int* __restrict__ gstart, int n) {
    int g = blockIdx.x * blockDim.x + threadIdx.x;
    if (g > NGRAPH) return;
    if (g == NGRAPH) { gstart[NGRAPH] = n; return; }
    int lo = 0, hi = n;
    while (lo < hi) {
        int mid = (lo + hi) >> 1;
        if (batch[mid] < g) lo = mid + 1; else hi = mid;
    }
    gstart[g] = lo;
}

__global__ __launch_bounds__(256) void pool2(const float* __restrict__ h,
                                             const int* __restrict__ gstart,
                                             float* __restrict__ out) {
    __shared__ float red[4][64];
    int g = blockIdx.x;
    int beg = gstart[g], end = gstart[g + 1];
    int w = threadIdx.x >> 6, lane = threadIdx.x & 63;
    float acc = 0.0f;
    for (int i = beg + w; i < end; i += 4)
        acc += h[(size_t)i * FDIM + lane];
    red[w][lane] = acc;
    __syncthreads();
    if (w == 0) {
        float tot = red[0][lane] + red[1][lane] + red[2][lane] + red[3][lane];
        float cnt = (float)(end - beg);
        out[(size_t)g * FDIM + lane] = tot / fmaxf(cnt, 1.0f);
    }
}

extern "C" void kernel_launch(void* const* d_in, const int* in_sizes, int n_in,
                              void* d_out, int out_size, void* d_ws, size_t ws_size,
                              hipStream_t stream) {
    const float* x     = (const float*)d_in[0];
    const int*   ei    = (const int*)d_in[1];
    const int*   batch = (const int*)d_in[2];
    const float* W1    = (const float*)d_in[3];
    const float* b1    = (const float*)d_in[4];
    const float* W2    = (const float*)d_in[5];
    const float* b2    = (const float*)d_in[6];
    const float* W3    = (const float*)d_in[7];
    const float* b3    = (const float*)d_in[8];
    float* out = (float*)d_out;

    const int N = N_NODES, E = N_EDGES;
    const int* src = ei;
    const int* dst = ei + E;

    // -------- workspace partition (bytes, 256-aligned) --------
    char* ws = (char*)d_ws;
    float*          dinv    = (float*)         (ws + 0);         //   400000 B
    int*            offsets = (int*)           (ws + 400128);    //   400004 B (N+1)
    int*            csr_src = (int*)           (ws + 800256);    //  6400000 B
    float*          bufA    = (float*)         (ws + 7200384);   // 25600000 B (fp32 gather out / gemm in)
    unsigned short* hbf     = (unsigned short*)(ws + 32800384);  // 12800000 B (bf16 gemm out / gather in)
    int*            gstart  = (int*)           (ws + 45600384);  //     2052 B
    int*            perm    = (int*)           (ws + 45602560);  //   400000 B
    int*            scannedD= (int*)           (ws + 46002688);  //    32772 B (MAXD*DWG+1)
    int*            blocksumsD=(int*)          (ws + 46035584);  //      512 B
    // aliases into bufA (dead before layer kernels):
    int* scannedH   = (int*)(ws + 7200384);            // NB*NWG+1 ints (~801 KB)
    int* blocksumsH = (int*)(ws + 8201216);            // 196 ints
    int* ebin       = (int*)(ws + 8202240);            // E ints (6.4 MB)

    // -------- bucketed counting sort -> CSR + degree/dinv/offsets --------
    hist_kernel<<<NWG, 256, 0, stream>>>(dst, scannedH, E);
    const int nH = NB * NWG;                // 200192
    const int nScanH = (nH + 1023) / 1024;  // 196
    scan_block<<<nScanH, 256, 0, stream>>>(scannedH, scannedH, blocksumsH, nH);
    scan_top<<<1, 64, 0, stream>>>(blocksumsH, nScanH, scannedH, nH);
    scan_add<<<(nH + 255) / 256, 256, 0, stream>>>(scannedH, blocksumsH, nH);
    bin_kernel<<<NWG, 256, 0, stream>>>(src, dst, scannedH, ebin, E);
    csr_sort2<<<NB, 256, 0, stream>>>(ebin, scannedH, csr_src, offsets, dinv, E);

    // -------- degree-sorted node permutation --------
    histD_kernel<<<DWG, 256, 0, stream>>>(offsets, scannedD);
    const int nD = MAXD * DWG;              // 8192
    const int nScanD = (nD + 1023) / 1024;  // 8
    scan_block<<<nScanD, 256, 0, stream>>>(scannedD, scannedD, blocksumsD, nD);
    scan_top<<<1, 64, 0, stream>>>(blocksumsD, nScanD, scannedD, nD);
    scan_add<<<(nD + 255) / 256, 256, 0, stream>>>(scannedD, blocksumsD, nD);
    binD_kernel<<<DWG, 256, 0, stream>>>(offsets, scannedD, perm);

    // -------- graph boundaries (batch sorted) --------
    gstart_kernel<<<3, 256, 0, stream>>>(batch, gstart, N);

    const int gemmGrid   = (N + 63) / 64;
    const int gatherGrid = (N * 8 + 255) / 256;   // 8 lanes per node

    // ---- layer 1 ----  (gemm prescales by dinv, outputs bf16; gather accumulates fp32)
    gemm64<<<gemmGrid, 256, 0, stream>>>(x, W1, dinv, hbf, N);
    gather_pn<<<gatherGrid, 256, 0, stream>>>(hbf, csr_src, offsets, perm, dinv, b1, bufA, N, 1);

    // ---- layer 2 ----
    gemm64<<<gemmGrid, 256, 0, stream>>>(bufA, W2, dinv, hbf, N);
    gather_pn<<<gatherGrid, 256, 0, stream>>>(hbf, csr_src, offsets, perm, dinv, b2, bufA, N, 1);

    // ---- layer 3 ----
    gemm64<<<gemmGrid, 256, 0, stream>>>(bufA, W3, dinv, hbf, N);
    gather_pn<<<gatherGrid, 256, 0, stream>>>(hbf, csr_src, offsets, perm, dinv, b3, bufA, N, 0);

    // ---- global mean pool (no atomics) ----
    pool2<<<NGRAPH, 256, 0, stream>>>(bufA, gstart, out);
}

// Round 11
// 274.903 us; speedup vs baseline: 1.9536x; 1.0445x over previous
//
#include <hip/hip_runtime.h>

#define N_NODES 100000
#define N_EDGES 1600000
#define FDIM 64
#define NGRAPH 512
#define NB 782          // dst buckets of 128 nodes
#define NWG 1024        // workgroups in hist/bin passes
#define CHUNK 1563      // ceil(E / NWG)
#define DWG 64          // workgroups for degree binning
#define DCHUNK ((N_NODES + DWG - 1) / DWG)
#define MAXD 128        // degree clamp for counting sort

__device__ __forceinline__ unsigned short f2bf(float v) {
    unsigned int x = __float_as_uint(v);
    x += 0x7FFF + ((x >> 16) & 1);          // RTNE
    return (unsigned short)(x >> 16);
}

// ================= scan kernels =================
__global__ void scan_block(const int* __restrict__ in, int* __restrict__ excl,
                           int* __restrict__ blocksums, int n) {
    __shared__ int lds[256];
    int t = threadIdx.x;
    int base = blockIdx.x * 1024 + t * 4;
    int v0 = (base     < n) ? in[base]     : 0;
    int v1 = (base + 1 < n) ? in[base + 1] : 0;
    int v2 = (base + 2 < n) ? in[base + 2] : 0;
    int v3 = (base + 3 < n) ? in[base + 3] : 0;
    int s = v0 + v1 + v2 + v3;
    lds[t] = s;
    __syncthreads();
    for (int off = 1; off < 256; off <<= 1) {
        int x = (t >= off) ? lds[t - off] : 0;
        __syncthreads();
        lds[t] += x;
        __syncthreads();
    }
    int thrExcl = lds[t] - s;
    if (t == 255) blocksums[blockIdx.x] = lds[255];
    if (base     < n) excl[base]     = thrExcl;
    if (base + 1 < n) excl[base + 1] = thrExcl + v0;
    if (base + 2 < n) excl[base + 2] = thrExcl + v0 + v1;
    if (base + 3 < n) excl[base + 3] = thrExcl + v0 + v1 + v2;
}

// single-block exclusive scan of blocksums (nb <= 1024), total -> out[n]
__global__ void scan_top2(int* __restrict__ blocksums, int nb, int* __restrict__ out, int n) {
    __shared__ int lds[256];
    int t = threadIdx.x;
    int base = t * 4;
    int v0 = (base     < nb) ? blocksums[base]     : 0;
    int v1 = (base + 1 < nb) ? blocksums[base + 1] : 0;
    int v2 = (base + 2 < nb) ? blocksums[base + 2] : 0;
    int v3 = (base + 3 < nb) ? blocksums[base + 3] : 0;
    int s = v0 + v1 + v2 + v3;
    lds[t] = s;
    __syncthreads();
    for (int off = 1; off < 256; off <<= 1) {
        int x = (t >= off) ? lds[t - off] : 0;
        __syncthreads();
        lds[t] += x;
        __syncthreads();
    }
    int excl = lds[t] - s;
    if (base     < nb) blocksums[base]     = excl;
    if (base + 1 < nb) blocksums[base + 1] = excl + v0;
    if (base + 2 < nb) blocksums[base + 2] = excl + v0 + v1;
    if (base + 3 < nb) blocksums[base + 3] = excl + v0 + v1 + v2;
    if (t == 255) out[n] = lds[255];
}

__global__ void scan_add(int* __restrict__ out, const int* __restrict__ blocksums, int n) {
    int i = blockIdx.x * blockDim.x + threadIdx.x;
    if (i < n) out[i] += blocksums[i >> 10];
}

// ================= pass A: per-wg bucket histogram =================
__global__ __launch_bounds__(256) void hist_kernel(const int* __restrict__ dst,
                                                   int* __restrict__ hist, int E) {
    __shared__ int h[NB];
    int t = threadIdx.x, wg = blockIdx.x;
    for (int i = t; i < NB; i += 256) h[i] = 0;
    __syncthreads();
    int beg = wg * CHUNK, end = min(beg + CHUNK, E);
    for (int i = beg + t; i < end; i += 256) atomicAdd(&h[dst[i] >> 7], 1);
    __syncthreads();
    for (int i = t; i < NB; i += 256) hist[i * NWG + wg] = h[i];
}

// ================= pass B: binned append (LDS cursors, packed 4B edges) =================
__global__ __launch_bounds__(256) void bin_kernel(const int* __restrict__ src,
                                                  const int* __restrict__ dst,
                                                  const int* __restrict__ scannedH,
                                                  int* __restrict__ ebin, int E) {
    __shared__ int base[NB];
    __shared__ int cur[NB];
    int t = threadIdx.x, wg = blockIdx.x;
    for (int i = t; i < NB; i += 256) { base[i] = scannedH[i * NWG + wg]; cur[i] = 0; }
    __syncthreads();
    int beg = wg * CHUNK, end = min(beg + CHUNK, E);
    for (int i = beg + t; i < end; i += 256) {
        int d = dst[i];
        int b = d >> 7;
        int p = base[b] + atomicAdd(&cur[b], 1);
        ebin[p] = ((d & 127) << 17) | src[i];
    }
}

// ================= pass C: per-bucket sort + degree + dinv + offsets =================
__global__ __launch_bounds__(256) void csr_sort2(const int* __restrict__ ebin,
                                                 const int* __restrict__ scannedH,
                                                 int* __restrict__ csr_src,
                                                 int* __restrict__ offsets,
                                                 float* __restrict__ dinv, int E) {
    __shared__ int cnt[128];
    __shared__ int seg[128];
    __shared__ int cur[128];
    __shared__ int buf[4352];
    int t = threadIdx.x, b = blockIdx.x;
    int nbase = b << 7;
    int nodes = min(128, N_NODES - nbase);
    int bstart = scannedH[b * NWG];
    int bend = (b == NB - 1) ? E : scannedH[(b + 1) * NWG];
    if (t < 128) cnt[t] = 0;
    __syncthreads();
    for (int i = bstart + t; i < bend; i += 256) atomicAdd(&cnt[ebin[i] >> 17], 1);
    __syncthreads();
    if (t < 128) seg[t] = cnt[t];
    __syncthreads();
    for (int off = 1; off < 128; off <<= 1) {
        int v = 0;
        if (t < 128 && t >= off) v = seg[t - off];
        __syncthreads();
        if (t < 128) seg[t] += v;
        __syncthreads();
    }
    if (t < nodes) {
        int excl = seg[t] - cnt[t];
        offsets[nbase + t] = bstart + excl;
        dinv[nbase + t] = rsqrtf((float)cnt[t] + 1.0f);   // +1 self loop
        cur[t] = excl;
    }
    if (b == 0 && t == 0) offsets[N_NODES] = E;
    __syncthreads();
    for (int i = bstart + t; i < bend; i += 256) {
        int v = ebin[i];
        int p = atomicAdd(&cur[v >> 17], 1);
        buf[p] = v & 0x1FFFF;
    }
    __syncthreads();
    int span = bend - bstart;
    for (int i = t; i < span; i += 256) csr_src[bstart + i] = buf[i];
}

// ================= degree counting sort: nodes grouped by degree =================
__global__ __launch_bounds__(256) void histD_kernel(const int* __restrict__ offsets,
                                                    int* __restrict__ histD) {
    __shared__ int h[MAXD];
    int t = threadIdx.x, wg = blockIdx.x;
    if (t < MAXD) h[t] = 0;
    __syncthreads();
    int beg = wg * DCHUNK, end = min(beg + DCHUNK, N_NODES);
    for (int i = beg + t; i < end; i += 256) {
        int d = min(offsets[i + 1] - offsets[i], MAXD - 1);
        atomicAdd(&h[d], 1);
    }
    __syncthreads();
    if (t < MAXD) histD[t * DWG + wg] = h[t];
}

__global__ __launch_bounds__(256) void binD_kernel(const int* __restrict__ offsets,
                                                   const int* __restrict__ scannedD,
                                                   int* __restrict__ perm) {
    __shared__ int base[MAXD];
    __shared__ int cur[MAXD];
    int t = threadIdx.x, wg = blockIdx.x;
    if (t < MAXD) { base[t] = scannedD[t * DWG + wg]; cur[t] = 0; }
    __syncthreads();
    int beg = wg * DCHUNK, end = min(beg + DCHUNK, N_NODES);
    for (int i = beg + t; i < end; i += 256) {
        int d = min(offsets[i + 1] - offsets[i], MAXD - 1);
        int pos = base[d] + atomicAdd(&cur[d], 1);
        perm[pos] = i;
    }
}

// ================= fp32 GEMM (register-tiled 4x4) -> bf16: Hs = bf16((X@W)*dinv) ======
__global__ __launch_bounds__(256) void gemm64(const float* __restrict__ X,
                                              const float* __restrict__ W,
                                              const float* __restrict__ dinv,
                                              unsigned short* __restrict__ Hout, int n) {
    __shared__ float Ws[64 * 68];
    __shared__ float Xs[64 * 68];
    int t = threadIdx.x;
    int r0 = blockIdx.x * 64;

    #pragma unroll
    for (int kk = 0; kk < 16; ++kk) {
        int idx = t + kk * 256;
        int r = idx >> 6, c = idx & 63;
        Ws[r * 68 + c] = W[idx];
        float v = (r0 + r < n) ? X[(size_t)(r0 + r) * FDIM + c] : 0.0f;
        Xs[c * 68 + r] = v;
    }
    __syncthreads();

    int rg = (t >> 4) << 2;
    int cg = (t & 15) << 2;
    float4 acc0 = {0, 0, 0, 0}, acc1 = {0, 0, 0, 0};
    float4 acc2 = {0, 0, 0, 0}, acc3 = {0, 0, 0, 0};

    #pragma unroll 8
    for (int k = 0; k < 64; ++k) {
        float4 xv = *(const float4*)&Xs[k * 68 + rg];
        float4 wv = *(const float4*)&Ws[k * 68 + cg];
        acc0.x += xv.x * wv.x; acc0.y += xv.x * wv.y; acc0.z += xv.x * wv.z; acc0.w += xv.x * wv.w;
        acc1.x += xv.y * wv.x; acc1.y += xv.y * wv.y; acc1.z += xv.y * wv.z; acc1.w += xv.y * wv.w;
        acc2.x += xv.z * wv.x; acc2.y += xv.z * wv.y; acc2.z += xv.z * wv.z; acc2.w += xv.z * wv.w;
        acc3.x += xv.w * wv.x; acc3.y += xv.w * wv.y; acc3.z += xv.w * wv.z; acc3.w += xv.w * wv.w;
    }

    float4 accs[4] = {acc0, acc1, acc2, acc3};
    #pragma unroll
    for (int i = 0; i < 4; ++i) {
        int row = r0 + rg + i;
        if (row < n) {
            float sc = dinv[row];
            unsigned int u0 = (unsigned int)f2bf(accs[i].x * sc) | ((unsigned int)f2bf(accs[i].y * sc) << 16);
            unsigned int u1 = (unsigned int)f2bf(accs[i].z * sc) | ((unsigned int)f2bf(accs[i].w * sc) << 16);
            *(uint2*)&Hout[(size_t)row * FDIM + cg] = make_uint2(u0, u1);
        }
    }
}

// ================= gather, 8 lanes own one node, unroll-4 =================
__global__ __launch_bounds__(256) void gather_pn(const unsigned short* __restrict__ hs,
                                                 const int* __restrict__ csr_src,
                                                 const int* __restrict__ offsets,
                                                 const int* __restrict__ perm,
                                                 const float* __restrict__ dinv,
                                                 const float* __restrict__ bias,
                                                 float* __restrict__ outb,
                                                 int n, int do_relu) {
    int slot = (blockIdx.x * 256 + threadIdx.x) >> 3;
    int p = threadIdx.x & 7;
    if (slot >= n) return;
    int node = perm[slot];
    int beg = offsets[node], end = offsets[node + 1];

    float a0 = 0, a1 = 0, a2 = 0, a3 = 0, a4 = 0, a5 = 0, a6 = 0, a7 = 0;
    int k = beg;
    for (; k + 3 < end; k += 4) {
        int s0 = csr_src[k], s1 = csr_src[k + 1], s2 = csr_src[k + 2], s3 = csr_src[k + 3];
        uint4 v0 = *(const uint4*)(hs + ((size_t)s0 << 6) + (p << 3));
        uint4 v1 = *(const uint4*)(hs + ((size_t)s1 << 6) + (p << 3));
        uint4 v2 = *(const uint4*)(hs + ((size_t)s2 << 6) + (p << 3));
        uint4 v3 = *(const uint4*)(hs + ((size_t)s3 << 6) + (p << 3));
        a0 += __uint_as_float(v0.x << 16); a1 += __uint_as_float(v0.x & 0xFFFF0000u);
        a2 += __uint_as_float(v0.y << 16); a3 += __uint_as_float(v0.y & 0xFFFF0000u);
        a4 += __uint_as_float(v0.z << 16); a5 += __uint_as_float(v0.z & 0xFFFF0000u);
        a6 += __uint_as_float(v0.w << 16); a7 += __uint_as_float(v0.w & 0xFFFF0000u);
        a0 += __uint_as_float(v1.x << 16); a1 += __uint_as_float(v1.x & 0xFFFF0000u);
        a2 += __uint_as_float(v1.y << 16); a3 += __uint_as_float(v1.y & 0xFFFF0000u);
        a4 += __uint_as_float(v1.z << 16); a5 += __uint_as_float(v1.z & 0xFFFF0000u);
        a6 += __uint_as_float(v1.w << 16); a7 += __uint_as_float(v1.w & 0xFFFF0000u);
        a0 += __uint_as_float(v2.x << 16); a1 += __uint_as_float(v2.x & 0xFFFF0000u);
        a2 += __uint_as_float(v2.y << 16); a3 += __uint_as_float(v2.y & 0xFFFF0000u);
        a4 += __uint_as_float(v2.z << 16); a5 += __uint_as_float(v2.z & 0xFFFF0000u);
        a6 += __uint_as_float(v2.w << 16); a7 += __uint_as_float(v2.w & 0xFFFF0000u);
        a0 += __uint_as_float(v3.x << 16); a1 += __uint_as_float(v3.x & 0xFFFF0000u);
        a2 += __uint_as_float(v3.y << 16); a3 += __uint_as_float(v3.y & 0xFFFF0000u);
        a4 += __uint_as_float(v3.z << 16); a5 += __uint_as_float(v3.z & 0xFFFF0000u);
        a6 += __uint_as_float(v3.w << 16); a7 += __uint_as_float(v3.w & 0xFFFF0000u);
    }
    for (; k < end; ++k) {
        int s0 = csr_src[k];
        uint4 v0 = *(const uint4*)(hs + ((size_t)s0 << 6) + (p << 3));
        a0 += __uint_as_float(v0.x << 16); a1 += __uint_as_float(v0.x & 0xFFFF0000u);
        a2 += __uint_as_float(v0.y << 16); a3 += __uint_as_float(v0.y & 0xFFFF0000u);
        a4 += __uint_as_float(v0.z << 16); a5 += __uint_as_float(v0.z & 0xFFFF0000u);
        a6 += __uint_as_float(v0.w << 16); a7 += __uint_as_float(v0.w & 0xFFFF0000u);
    }
    // self-loop row
    uint4 sv = *(const uint4*)(hs + ((size_t)node << 6) + (p << 3));
    float dd = dinv[node];
    int fb = p << 3;
    const float4* bp = (const float4*)(bias + fb);
    float4 bv0 = bp[0], bv1 = bp[1];
    float o0 = dd * (a0 + __uint_as_float(sv.x << 16))        + bv0.x;
    float o1 = dd * (a1 + __uint_as_float(sv.x & 0xFFFF0000u)) + bv0.y;
    float o2 = dd * (a2 + __uint_as_float(sv.y << 16))        + bv0.z;
    float o3 = dd * (a3 + __uint_as_float(sv.y & 0xFFFF0000u)) + bv0.w;
    float o4 = dd * (a4 + __uint_as_float(sv.z << 16))        + bv1.x;
    float o5 = dd * (a5 + __uint_as_float(sv.z & 0xFFFF0000u)) + bv1.y;
    float o6 = dd * (a6 + __uint_as_float(sv.w << 16))        + bv1.z;
    float o7 = dd * (a7 + __uint_as_float(sv.w & 0xFFFF0000u)) + bv1.w;
    if (do_relu) {
        o0 = fmaxf(o0, 0.0f); o1 = fmaxf(o1, 0.0f); o2 = fmaxf(o2, 0.0f); o3 = fmaxf(o3, 0.0f);
        o4 = fmaxf(o4, 0.0f); o5 = fmaxf(o5, 0.0f); o6 = fmaxf(o6, 0.0f); o7 = fmaxf(o7, 0.0f);
    }
    float4* op = (float4*)(outb + (size_t)node * FDIM + fb);
    op[0] = make_float4(o0, o1, o2, o3);
    op[1] = make_float4(o4, o5, o6, o7);
}

// ================= pooling (batch sorted -> segmented reduction) =================
__global__ void gstart_kernel(const int* __restrict__ batch, int* __restrict__ gstart, int n) {
    int g = blockIdx.x * blockDim.x + threadIdx.x;
    if (g > NGRAPH) return;
    if (g == NGRAPH) { gstart[NGRAPH] = n; return; }
    int lo = 0, hi = n;
    while (lo < hi) {
        int mid = (lo + hi) >> 1;
        if (batch[mid] < g) lo = mid + 1; else hi = mid;
    }
    gstart[g] = lo;
}

__global__ __launch_bounds__(256) void pool2(const float* __restrict__ h,
                                             const int* __restrict__ gstart,
                                             float* __restrict__ out) {
    __shared__ float red[4][64];
    int g = blockIdx.x;
    int beg = gstart[g], end = gstart[g + 1];
    int w = threadIdx.x >> 6, lane = threadIdx.x & 63;
    float acc = 0.0f;
    for (int i = beg + w; i < end; i += 4)
        acc += h[(size_t)i * FDIM + lane];
    red[w][lane] = acc;
    __syncthreads();
    if (w == 0) {
        float tot = red[0][lane] + red[1][lane] + red[2][lane] + red[3][lane];
        float cnt = (float)(end - beg);
        out[(size_t)g * FDIM + lane] = tot / fmaxf(cnt, 1.0f);
    }
}

extern "C" void kernel_launch(void* const* d_in, const int* in_sizes, int n_in,
                              void* d_out, int out_size, void* d_ws, size_t ws_size,
                              hipStream_t stream) {
    const float* x     = (const float*)d_in[0];
    const int*   ei    = (const int*)d_in[1];
    const int*   batch = (const int*)d_in[2];
    const float* W1    = (const float*)d_in[3];
    const float* b1    = (const float*)d_in[4];
    const float* W2    = (const float*)d_in[5];
    const float* b2    = (const float*)d_in[6];
    const float* W3    = (const float*)d_in[7];
    const float* b3    = (const float*)d_in[8];
    float* out = (float*)d_out;

    const int N = N_NODES, E = N_EDGES;
    const int* src = ei;
    const int* dst = ei + E;

    // -------- workspace partition (bytes, 256-aligned) --------
    char* ws = (char*)d_ws;
    float*          dinv    = (float*)         (ws + 0);         //   400000 B
    int*            offsets = (int*)           (ws + 400128);    //   400004 B (N+1)
    int*            csr_src = (int*)           (ws + 800256);    //  6400000 B
    float*          bufA    = (float*)         (ws + 7200384);   // 25600000 B (fp32 gather out / gemm in)
    unsigned short* hbf     = (unsigned short*)(ws + 32800384);  // 12800000 B (bf16 gemm out / gather in)
    int*            gstart  = (int*)           (ws + 45600384);  //     2052 B
    int*            perm    = (int*)           (ws + 45602560);  //   400000 B
    int*            scannedD= (int*)           (ws + 46002688);  //    32772 B (MAXD*DWG+1)
    int*            blocksumsD=(int*)          (ws + 46035584);  //      512 B
    // aliases into bufA (dead before layer kernels):
    int* scannedH   = (int*)(ws + 7200384);            // NB*NWG+1 ints (~3.2 MB)
    int* blocksumsH = (int*)(ws + 10403584);           // 783 ints
    int* ebin       = (int*)(ws + 10407936);           // E ints (6.4 MB)

    // -------- bucketed counting sort -> CSR + degree/dinv/offsets --------
    hist_kernel<<<NWG, 256, 0, stream>>>(dst, scannedH, E);
    const int nH = NB * NWG;                // 800768
    const int nScanH = (nH + 1023) / 1024;  // 783
    scan_block<<<nScanH, 256, 0, stream>>>(scannedH, scannedH, blocksumsH, nH);
    scan_top2<<<1, 256, 0, stream>>>(blocksumsH, nScanH, scannedH, nH);
    scan_add<<<(nH + 255) / 256, 256, 0, stream>>>(scannedH, blocksumsH, nH);
    bin_kernel<<<NWG, 256, 0, stream>>>(src, dst, scannedH, ebin, E);
    csr_sort2<<<NB, 256, 0, stream>>>(ebin, scannedH, csr_src, offsets, dinv, E);

    // -------- degree-sorted node permutation --------
    histD_kernel<<<DWG, 256, 0, stream>>>(offsets, scannedD);
    const int nD = MAXD * DWG;              // 8192
    const int nScanD = (nD + 1023) / 1024;  // 8
    scan_block<<<nScanD, 256, 0, stream>>>(scannedD, scannedD, blocksumsD, nD);
    scan_top2<<<1, 256, 0, stream>>>(blocksumsD, nScanD, scannedD, nD);
    scan_add<<<(nD + 255) / 256, 256, 0, stream>>>(scannedD, blocksumsD, nD);
    binD_kernel<<<DWG, 256, 0, stream>>>(offsets, scannedD, perm);

    // -------- graph boundaries (batch sorted) --------
    gstart_kernel<<<3, 256, 0, stream>>>(batch, gstart, N);

    const int gemmGrid   = (N + 63) / 64;
    const int gatherGrid = (N * 8 + 255) / 256;   // 8 lanes per node

    // ---- layer 1 ----  (gemm prescales by dinv, outputs bf16; gather accumulates fp32)
    gemm64<<<gemmGrid, 256, 0, stream>>>(x, W1, dinv, hbf, N);
    gather_pn<<<gatherGrid, 256, 0, stream>>>(hbf, csr_src, offsets, perm, dinv, b1, bufA, N, 1);

    // ---- layer 2 ----
    gemm64<<<gemmGrid, 256, 0, stream>>>(bufA, W2, dinv, hbf, N);
    gather_pn<<<gatherGrid, 256, 0, stream>>>(hbf, csr_src, offsets, perm, dinv, b2, bufA, N, 1);

    // ---- layer 3 ----
    gemm64<<<gemmGrid, 256, 0, stream>>>(bufA, W3, dinv, hbf, N);
    gather_pn<<<gatherGrid, 256, 0, stream>>>(hbf, csr_src, offsets, perm, dinv, b3, bufA, N, 0);

    // ---- global mean pool (no atomics) ----
    pool2<<<NGRAPH, 256, 0, stream>>>(bufA, gstart, out);
}

// Round 12
// 272.103 us; speedup vs baseline: 1.9737x; 1.0103x over previous
//
#include <hip/hip_runtime.h>

#define N_NODES 100000
#define N_EDGES 1600000
#define FDIM 64
#define NGRAPH 512
#define NB 782          // dst buckets of 128 nodes
#define NBP 784         // padded pitch for wg-major hist rows
#define NWG 512         // workgroups in hist/bin passes
#define CHUNK 3125      // E / NWG
#define DWG 64          // workgroups for degree binning
#define DCHUNK ((N_NODES + DWG - 1) / DWG)
#define MAXD 128        // degree clamp for counting sort

__device__ __forceinline__ unsigned short f2bf(float v) {
    unsigned int x = __float_as_uint(v);
    x += 0x7FFF + ((x >> 16) & 1);          // RTNE
    return (unsigned short)(x >> 16);
}

// ================= scan kernels =================
__global__ void scan_block(const int* __restrict__ in, int* __restrict__ excl,
                           int* __restrict__ blocksums, int n) {
    __shared__ int lds[256];
    int t = threadIdx.x;
    int base = blockIdx.x * 1024 + t * 4;
    int v0 = (base     < n) ? in[base]     : 0;
    int v1 = (base + 1 < n) ? in[base + 1] : 0;
    int v2 = (base + 2 < n) ? in[base + 2] : 0;
    int v3 = (base + 3 < n) ? in[base + 3] : 0;
    int s = v0 + v1 + v2 + v3;
    lds[t] = s;
    __syncthreads();
    for (int off = 1; off < 256; off <<= 1) {
        int x = (t >= off) ? lds[t - off] : 0;
        __syncthreads();
        lds[t] += x;
        __syncthreads();
    }
    int thrExcl = lds[t] - s;
    if (t == 255) blocksums[blockIdx.x] = lds[255];
    if (base     < n) excl[base]     = thrExcl;
    if (base + 1 < n) excl[base + 1] = thrExcl + v0;
    if (base + 2 < n) excl[base + 2] = thrExcl + v0 + v1;
    if (base + 3 < n) excl[base + 3] = thrExcl + v0 + v1 + v2;
}

// single-block exclusive scan of blocksums (nb <= 1024)
__global__ void scan_top2(int* __restrict__ blocksums, int nb) {
    __shared__ int lds[256];
    int t = threadIdx.x;
    int base = t * 4;
    int v0 = (base     < nb) ? blocksums[base]     : 0;
    int v1 = (base + 1 < nb) ? blocksums[base + 1] : 0;
    int v2 = (base + 2 < nb) ? blocksums[base + 2] : 0;
    int v3 = (base + 3 < nb) ? blocksums[base + 3] : 0;
    int s = v0 + v1 + v2 + v3;
    lds[t] = s;
    __syncthreads();
    for (int off = 1; off < 256; off <<= 1) {
        int x = (t >= off) ? lds[t - off] : 0;
        __syncthreads();
        lds[t] += x;
        __syncthreads();
    }
    int excl = lds[t] - s;
    if (base     < nb) blocksums[base]     = excl;
    if (base + 1 < nb) blocksums[base + 1] = excl + v0;
    if (base + 2 < nb) blocksums[base + 2] = excl + v0 + v1;
    if (base + 3 < nb) blocksums[base + 3] = excl + v0 + v1 + v2;
}

__global__ void scan_add(int* __restrict__ out, const int* __restrict__ blocksums, int n) {
    int i = blockIdx.x * blockDim.x + threadIdx.x;
    if (i < n) out[i] += blocksums[i >> 10];
}

// single-block exclusive scan for n = 8192 (degree histogram)
__global__ __launch_bounds__(256) void scan_single(int* __restrict__ data, int n) {
    __shared__ int lds[256];
    int t = threadIdx.x;
    int loc[32];
    int base = t * 32;
    int s = 0;
    #pragma unroll
    for (int j = 0; j < 32; ++j) { loc[j] = (base + j < n) ? data[base + j] : 0; s += loc[j]; }
    lds[t] = s;
    __syncthreads();
    for (int off = 1; off < 256; off <<= 1) {
        int x = (t >= off) ? lds[t - off] : 0;
        __syncthreads();
        lds[t] += x;
        __syncthreads();
    }
    int run = lds[t] - s;
    #pragma unroll
    for (int j = 0; j < 32; ++j) {
        int v = loc[j];
        if (base + j < n) data[base + j] = run;
        run += v;
    }
}

// ================= 32x32 LDS transpose: dst[c*dpitch+r] = src[r*spitch+c] =================
__global__ __launch_bounds__(256) void transpose_k(const int* __restrict__ src, int* __restrict__ dst,
                                                   int R, int C, int spitch, int dpitch) {
    __shared__ int tile[32][33];
    int tilesC = (C + 31) >> 5;
    int bx = blockIdx.x % tilesC;
    int by = blockIdx.x / tilesC;
    int tx = threadIdx.x & 31, ty = threadIdx.x >> 5;   // 32 x 8
    int c = bx * 32 + tx;
    #pragma unroll
    for (int j = 0; j < 32; j += 8) {
        int r = by * 32 + ty + j;
        if (r < R && c < C) tile[ty + j][tx] = src[r * spitch + c];
    }
    __syncthreads();
    int rT = by * 32 + tx;
    #pragma unroll
    for (int j = 0; j < 32; j += 8) {
        int cT = bx * 32 + ty + j;
        if (cT < C && rT < R) dst[cT * dpitch + rT] = tile[tx][ty + j];
    }
}

// ================= pass A: per-wg bucket histogram (wg-major, coalesced) =================
__global__ __launch_bounds__(256) void hist_kernel(const int* __restrict__ dst,
                                                   int* __restrict__ histWG, int E) {
    __shared__ int h[NB];
    int t = threadIdx.x, wg = blockIdx.x;
    for (int i = t; i < NB; i += 256) h[i] = 0;
    __syncthreads();
    int beg = wg * CHUNK, end = min(beg + CHUNK, E);
    for (int i = beg + t; i < end; i += 256) atomicAdd(&h[dst[i] >> 7], 1);
    __syncthreads();
    for (int i = t; i < NB; i += 256) histWG[wg * NBP + i] = h[i];
}

// ================= pass B: binned append (wg-major base reads, unroll-2) =================
__global__ __launch_bounds__(256) void bin_kernel(const int* __restrict__ src,
                                                  const int* __restrict__ dst,
                                                  const int* __restrict__ baseWG,
                                                  int* __restrict__ ebin, int E) {
    __shared__ int base[NB];
    __shared__ int cur[NB];
    int t = threadIdx.x, wg = blockIdx.x;
    for (int i = t; i < NB; i += 256) { base[i] = baseWG[wg * NBP + i]; cur[i] = 0; }
    __syncthreads();
    int beg = wg * CHUNK, end = min(beg + CHUNK, E);
    for (int i = beg + t * 2; i < end; i += 512) {
        int d0 = dst[i], s0 = src[i];
        int b0 = d0 >> 7;
        int p0 = base[b0] + atomicAdd(&cur[b0], 1);
        ebin[p0] = ((d0 & 127) << 17) | s0;
        if (i + 1 < end) {
            int d1 = dst[i + 1], s1 = src[i + 1];
            int b1 = d1 >> 7;
            int p1 = base[b1] + atomicAdd(&cur[b1], 1);
            ebin[p1] = ((d1 & 127) << 17) | s1;
        }
    }
}

// ================= pass C: per-bucket sort + degree + dinv + offsets =================
__global__ __launch_bounds__(256) void csr_sort2(const int* __restrict__ ebin,
                                                 const int* __restrict__ scannedT,
                                                 int* __restrict__ csr_src,
                                                 int* __restrict__ offsets,
                                                 float* __restrict__ dinv, int E) {
    __shared__ int cnt[128];
    __shared__ int seg[128];
    __shared__ int cur[128];
    __shared__ int buf[4352];
    int t = threadIdx.x, b = blockIdx.x;
    int nbase = b << 7;
    int nodes = min(128, N_NODES - nbase);
    int bstart = scannedT[b * NWG];
    int bend = (b == NB - 1) ? E : scannedT[(b + 1) * NWG];
    if (t < 128) cnt[t] = 0;
    __syncthreads();
    for (int i = bstart + t; i < bend; i += 256) atomicAdd(&cnt[ebin[i] >> 17], 1);
    __syncthreads();
    if (t < 128) seg[t] = cnt[t];
    __syncthreads();
    for (int off = 1; off < 128; off <<= 1) {
        int v = 0;
        if (t < 128 && t >= off) v = seg[t - off];
        __syncthreads();
        if (t < 128) seg[t] += v;
        __syncthreads();
    }
    if (t < nodes) {
        int excl = seg[t] - cnt[t];
        offsets[nbase + t] = bstart + excl;
        dinv[nbase + t] = rsqrtf((float)cnt[t] + 1.0f);   // +1 self loop
        cur[t] = excl;
    }
    if (b == 0 && t == 0) offsets[N_NODES] = E;
    __syncthreads();
    for (int i = bstart + t; i < bend; i += 256) {
        int v = ebin[i];
        int p = atomicAdd(&cur[v >> 17], 1);
        buf[p] = v & 0x1FFFF;
    }
    __syncthreads();
    int span = bend - bstart;
    for (int i = t; i < span; i += 256) csr_src[bstart + i] = buf[i];
}

// ================= degree counting sort: nodes grouped by degree =================
__global__ __launch_bounds__(256) void histD_kernel(const int* __restrict__ offsets,
                                                    int* __restrict__ histD) {
    __shared__ int h[MAXD];
    int t = threadIdx.x, wg = blockIdx.x;
    if (t < MAXD) h[t] = 0;
    __syncthreads();
    int beg = wg * DCHUNK, end = min(beg + DCHUNK, N_NODES);
    for (int i = beg + t; i < end; i += 256) {
        int d = min(offsets[i + 1] - offsets[i], MAXD - 1);
        atomicAdd(&h[d], 1);
    }
    __syncthreads();
    if (t < MAXD) histD[t * DWG + wg] = h[t];
}

__global__ __launch_bounds__(256) void binD_kernel(const int* __restrict__ offsets,
                                                   const int* __restrict__ scannedD,
                                                   int* __restrict__ perm) {
    __shared__ int base[MAXD];
    __shared__ int cur[MAXD];
    int t = threadIdx.x, wg = blockIdx.x;
    if (t < MAXD) { base[t] = scannedD[t * DWG + wg]; cur[t] = 0; }
    __syncthreads();
    int beg = wg * DCHUNK, end = min(beg + DCHUNK, N_NODES);
    for (int i = beg + t; i < end; i += 256) {
        int d = min(offsets[i + 1] - offsets[i], MAXD - 1);
        int pos = base[d] + atomicAdd(&cur[d], 1);
        perm[pos] = i;
    }
}

// ================= fp32 GEMM (register-tiled 4x4) -> bf16: Hs = bf16((X@W)*dinv) ======
__global__ __launch_bounds__(256) void gemm64(const float* __restrict__ X,
                                              const float* __restrict__ W,
                                              const float* __restrict__ dinv,
                                              unsigned short* __restrict__ Hout, int n) {
    __shared__ float Ws[64 * 68];
    __shared__ float Xs[64 * 68];
    int t = threadIdx.x;
    int r0 = blockIdx.x * 64;

    #pragma unroll
    for (int kk = 0; kk < 16; ++kk) {
        int idx = t + kk * 256;
        int r = idx >> 6, c = idx & 63;
        Ws[r * 68 + c] = W[idx];
        float v = (r0 + r < n) ? X[(size_t)(r0 + r) * FDIM + c] : 0.0f;
        Xs[c * 68 + r] = v;
    }
    __syncthreads();

    int rg = (t >> 4) << 2;
    int cg = (t & 15) << 2;
    float4 acc0 = {0, 0, 0, 0}, acc1 = {0, 0, 0, 0};
    float4 acc2 = {0, 0, 0, 0}, acc3 = {0, 0, 0, 0};

    #pragma unroll 8
    for (int k = 0; k < 64; ++k) {
        float4 xv = *(const float4*)&Xs[k * 68 + rg];
        float4 wv = *(const float4*)&Ws[k * 68 + cg];
        acc0.x += xv.x * wv.x; acc0.y += xv.x * wv.y; acc0.z += xv.x * wv.z; acc0.w += xv.x * wv.w;
        acc1.x += xv.y * wv.x; acc1.y += xv.y * wv.y; acc1.z += xv.y * wv.z; acc1.w += xv.y * wv.w;
        acc2.x += xv.z * wv.x; acc2.y += xv.z * wv.y; acc2.z += xv.z * wv.z; acc2.w += xv.z * wv.w;
        acc3.x += xv.w * wv.x; acc3.y += xv.w * wv.y; acc3.z += xv.w * wv.z; acc3.w += xv.w * wv.w;
    }

    float4 accs[4] = {acc0, acc1, acc2, acc3};
    #pragma unroll
    for (int i = 0; i < 4; ++i) {
        int row = r0 + rg + i;
        if (row < n) {
            float sc = dinv[row];
            unsigned int u0 = (unsigned int)f2bf(accs[i].x * sc) | ((unsigned int)f2bf(accs[i].y * sc) << 16);
            unsigned int u1 = (unsigned int)f2bf(accs[i].z * sc) | ((unsigned int)f2bf(accs[i].w * sc) << 16);
            *(uint2*)&Hout[(size_t)row * FDIM + cg] = make_uint2(u0, u1);
        }
    }
}

// ================= gather, 8 lanes own one node, unroll-4 =================
__global__ __launch_bounds__(256) void gather_pn(const unsigned short* __restrict__ hs,
                                                 const int* __restrict__ csr_src,
                                                 const int* __restrict__ offsets,
                                                 const int* __restrict__ perm,
                                                 const float* __restrict__ dinv,
                                                 const float* __restrict__ bias,
                                                 float* __restrict__ outb,
                                                 int n, int do_relu) {
    int slot = (blockIdx.x * 256 + threadIdx.x) >> 3;
    int p = threadIdx.x & 7;
    if (slot >= n) return;
    int node = perm[slot];
    int beg = offsets[node], end = offsets[node + 1];

    float a0 = 0, a1 = 0, a2 = 0, a3 = 0, a4 = 0, a5 = 0, a6 = 0, a7 = 0;
    int k = beg;
    for (; k + 3 < end; k += 4) {
        int s0 = csr_src[k], s1 = csr_src[k + 1], s2 = csr_src[k + 2], s3 = csr_src[k + 3];
        uint4 v0 = *(const uint4*)(hs + ((size_t)s0 << 6) + (p << 3));
        uint4 v1 = *(const uint4*)(hs + ((size_t)s1 << 6) + (p << 3));
        uint4 v2 = *(const uint4*)(hs + ((size_t)s2 << 6) + (p << 3));
        uint4 v3 = *(const uint4*)(hs + ((size_t)s3 << 6) + (p << 3));
        a0 += __uint_as_float(v0.x << 16); a1 += __uint_as_float(v0.x & 0xFFFF0000u);
        a2 += __uint_as_float(v0.y << 16); a3 += __uint_as_float(v0.y & 0xFFFF0000u);
        a4 += __uint_as_float(v0.z << 16); a5 += __uint_as_float(v0.z & 0xFFFF0000u);
        a6 += __uint_as_float(v0.w << 16); a7 += __uint_as_float(v0.w & 0xFFFF0000u);
        a0 += __uint_as_float(v1.x << 16); a1 += __uint_as_float(v1.x & 0xFFFF0000u);
        a2 += __uint_as_float(v1.y << 16); a3 += __uint_as_float(v1.y & 0xFFFF0000u);
        a4 += __uint_as_float(v1.z << 16); a5 += __uint_as_float(v1.z & 0xFFFF0000u);
        a6 += __uint_as_float(v1.w << 16); a7 += __uint_as_float(v1.w & 0xFFFF0000u);
        a0 += __uint_as_float(v2.x << 16); a1 += __uint_as_float(v2.x & 0xFFFF0000u);
        a2 += __uint_as_float(v2.y << 16); a3 += __uint_as_float(v2.y & 0xFFFF0000u);
        a4 += __uint_as_float(v2.z << 16); a5 += __uint_as_float(v2.z & 0xFFFF0000u);
        a6 += __uint_as_float(v2.w << 16); a7 += __uint_as_float(v2.w & 0xFFFF0000u);
        a0 += __uint_as_float(v3.x << 16); a1 += __uint_as_float(v3.x & 0xFFFF0000u);
        a2 += __uint_as_float(v3.y << 16); a3 += __uint_as_float(v3.y & 0xFFFF0000u);
        a4 += __uint_as_float(v3.z << 16); a5 += __uint_as_float(v3.z & 0xFFFF0000u);
        a6 += __uint_as_float(v3.w << 16); a7 += __uint_as_float(v3.w & 0xFFFF0000u);
    }
    for (; k < end; ++k) {
        int s0 = csr_src[k];
        uint4 v0 = *(const uint4*)(hs + ((size_t)s0 << 6) + (p << 3));
        a0 += __uint_as_float(v0.x << 16); a1 += __uint_as_float(v0.x & 0xFFFF0000u);
        a2 += __uint_as_float(v0.y << 16); a3 += __uint_as_float(v0.y & 0xFFFF0000u);
        a4 += __uint_as_float(v0.z << 16); a5 += __uint_as_float(v0.z & 0xFFFF0000u);
        a6 += __uint_as_float(v0.w << 16); a7 += __uint_as_float(v0.w & 0xFFFF0000u);
    }
    // self-loop row
    uint4 sv = *(const uint4*)(hs + ((size_t)node << 6) + (p << 3));
    float dd = dinv[node];
    int fb = p << 3;
    const float4* bp = (const float4*)(bias + fb);
    float4 bv0 = bp[0], bv1 = bp[1];
    float o0 = dd * (a0 + __uint_as_float(sv.x << 16))        + bv0.x;
    float o1 = dd * (a1 + __uint_as_float(sv.x & 0xFFFF0000u)) + bv0.y;
    float o2 = dd * (a2 + __uint_as_float(sv.y << 16))        + bv0.z;
    float o3 = dd * (a3 + __uint_as_float(sv.y & 0xFFFF0000u)) + bv0.w;
    float o4 = dd * (a4 + __uint_as_float(sv.z << 16))        + bv1.x;
    float o5 = dd * (a5 + __uint_as_float(sv.z & 0xFFFF0000u)) + bv1.y;
    float o6 = dd * (a6 + __uint_as_float(sv.w << 16))        + bv1.z;
    float o7 = dd * (a7 + __uint_as_float(sv.w & 0xFFFF0000u)) + bv1.w;
    if (do_relu) {
        o0 = fmaxf(o0, 0.0f); o1 = fmaxf(o1, 0.0f); o2 = fmaxf(o2, 0.0f); o3 = fmaxf(o3, 0.0f);
        o4 = fmaxf(o4, 0.0f); o5 = fmaxf(o5, 0.0f); o6 = fmaxf(o6, 0.0f); o7 = fmaxf(o7, 0.0f);
    }
    float4* op = (float4*)(outb + (size_t)node * FDIM + fb);
    op[0] = make_float4(o0, o1, o2, o3);
    op[1] = make_float4(o4, o5, o6, o7);
}

// ================= pooling (batch sorted -> segmented reduction) =================
__global__ void gstart_kernel(const int* __restrict__ batch, int* __restrict__ gstart, int n) {
    int g = blockIdx.x * blockDim.x + threadIdx.x;
    if (g > NGRAPH) return;
    if (g == NGRAPH) { gstart[NGRAPH] = n; return; }
    int lo = 0, hi = n;
    while (lo < hi) {
        int mid = (lo + hi) >> 1;
        if (batch[mid] < g) lo = mid + 1; else hi = mid;
    }
    gstart[g] = lo;
}

__global__ __launch_bounds__(256) void pool2(const float* __restrict__ h,
                                             const int* __restrict__ gstart,
                                             float* __restrict__ out) {
    __shared__ float red[4][64];
    int g = blockIdx.x;
    int beg = gstart[g], end = gstart[g + 1];
    int w = threadIdx.x >> 6, lane = threadIdx.x & 63;
    float acc = 0.0f;
    for (int i = beg + w; i < end; i += 4)
        acc += h[(size_t)i * FDIM + lane];
    red[w][lane] = acc;
    __syncthreads();
    if (w == 0) {
        float tot = red[0][lane] + red[1][lane] + red[2][lane] + red[3][lane];
        float cnt = (float)(end - beg);
        out[(size_t)g * FDIM + lane] = tot / fmaxf(cnt, 1.0f);
    }
}

extern "C" void kernel_launch(void* const* d_in, const int* in_sizes, int n_in,
                              void* d_out, int out_size, void* d_ws, size_t ws_size,
                              hipStream_t stream) {
    const float* x     = (const float*)d_in[0];
    const int*   ei    = (const int*)d_in[1];
    const int*   batch = (const int*)d_in[2];
    const float* W1    = (const float*)d_in[3];
    const float* b1    = (const float*)d_in[4];
    const float* W2    = (const float*)d_in[5];
    const float* b2    = (const float*)d_in[6];
    const float* W3    = (const float*)d_in[7];
    const float* b3    = (const float*)d_in[8];
    float* out = (float*)d_out;

    const int N = N_NODES, E = N_EDGES;
    const int* src = ei;
    const int* dst = ei + E;

    // -------- workspace partition (bytes, 256-aligned) --------
    char* ws = (char*)d_ws;
    float*          dinv    = (float*)         (ws + 0);         //   400000 B
    int*            offsets = (int*)           (ws + 400128);    //   400004 B (N+1)
    int*            csr_src = (int*)           (ws + 800256);    //  6400000 B
    float*          bufA    = (float*)         (ws + 7200384);   // 25600000 B (fp32 gather out / gemm in)
    unsigned short* hbf     = (unsigned short*)(ws + 32800384);  // 12800000 B (bf16 gemm out / gather in)
    int*            gstart  = (int*)           (ws + 45600384);  //     2052 B
    int*            perm    = (int*)           (ws + 45602560);  //   400000 B
    int*            scannedD= (int*)           (ws + 46002688);  //    32772 B (MAXD*DWG)
    // aliases into bufA (dead before layer kernels):
    int* histT      = (int*)(ws + 7200384);            // NB*NWG ints (1.6 MB), bucket-major (scanned in place)
    int* blocksumsH = (int*)(ws + 8803328);            // 391 ints
    int* histWG     = (int*)(ws + 8805376);            // NWG*NBP ints (1.6 MB), wg-major
    int* ebin       = (int*)(ws + 10411520);           // E ints (6.4 MB)

    // -------- bucketed counting sort -> CSR + degree/dinv/offsets --------
    hist_kernel<<<NWG, 256, 0, stream>>>(dst, histWG, E);
    // transpose wg-major -> bucket-major: histT[i*NWG + wg] = histWG[wg*NBP + i]
    {
        int tilesC = (NB + 31) / 32, tilesR = (NWG + 31) / 32;   // 25 x 16
        transpose_k<<<tilesC * tilesR, 256, 0, stream>>>(histWG, histT, NWG, NB, NBP, NWG);
    }
    const int nH = NB * NWG;                // 400384
    const int nScanH = (nH + 1023) / 1024;  // 391
    scan_block<<<nScanH, 256, 0, stream>>>(histT, histT, blocksumsH, nH);
    scan_top2<<<1, 256, 0, stream>>>(blocksumsH, nScanH);
    scan_add<<<(nH + 255) / 256, 256, 0, stream>>>(histT, blocksumsH, nH);
    // transpose scanned bases back to wg-major for bin's coalesced reads
    {
        int tilesC = (NWG + 31) / 32, tilesR = (NB + 31) / 32;   // 16 x 25
        transpose_k<<<tilesC * tilesR, 256, 0, stream>>>(histT, histWG, NB, NWG, NWG, NBP);
    }
    bin_kernel<<<NWG, 256, 0, stream>>>(src, dst, histWG, ebin, E);
    csr_sort2<<<NB, 256, 0, stream>>>(ebin, histT, csr_src, offsets, dinv, E);

    // -------- degree-sorted node permutation --------
    histD_kernel<<<DWG, 256, 0, stream>>>(offsets, scannedD);
    scan_single<<<1, 256, 0, stream>>>(scannedD, MAXD * DWG);    // 8192 = 256*32
    binD_kernel<<<DWG, 256, 0, stream>>>(offsets, scannedD, perm);

    // -------- graph boundaries (batch sorted) --------
    gstart_kernel<<<3, 256, 0, stream>>>(batch, gstart, N);

    const int gemmGrid   = (N + 63) / 64;
    const int gatherGrid = (N * 8 + 255) / 256;   // 8 lanes per node

    // ---- layer 1 ----  (gemm prescales by dinv, outputs bf16; gather accumulates fp32)
    gemm64<<<gemmGrid, 256, 0, stream>>>(x, W1, dinv, hbf, N);
    gather_pn<<<gatherGrid, 256, 0, stream>>>(hbf, csr_src, offsets, perm, dinv, b1, bufA, N, 1);

    // ---- layer 2 ----
    gemm64<<<gemmGrid, 256, 0, stream>>>(bufA, W2, dinv, hbf, N);
    gather_pn<<<gatherGrid, 256, 0, stream>>>(hbf, csr_src, offsets, perm, dinv, b2, bufA, N, 1);

    // ---- layer 3 ----
    gemm64<<<gemmGrid, 256, 0, stream>>>(bufA, W3, dinv, hbf, N);
    gather_pn<<<gatherGrid, 256, 0, stream>>>(hbf, csr_src, offsets, perm, dinv, b3, bufA, N, 0);

    // ---- global mean pool (no atomics) ----
    pool2<<<NGRAPH, 256, 0, stream>>>(bufA, gstart, out);
}